// Round 11
// baseline (1502.039 us; speedup 1.0000x reference)
//
#include <hip/hip_runtime.h>

#define EMB 64
#define BROWS 512            // rows per bucket
#define BSHIFT 9             // log2(BROWS)
#define CHUNK 4096           // edges per partition block
#define COLBITS 23
#define COLMASK ((1u << COLBITS) - 1u)
#define MROWS 64             // rows per MLP block
#define HPAD 66              // padded stride for hT

// bf16 pack (RNE)
__device__ __forceinline__ unsigned short f2bf(float f) {
    unsigned u = __float_as_uint(f);
    u = u + 0x7FFFu + ((u >> 16) & 1u);
    return (unsigned short)(u >> 16);
}

// K0: convert left (f32) -> left16 (bf16), 2 elems/thread
__global__ void convert_left_kernel(const float* __restrict__ left,
                                    unsigned* __restrict__ left16, int n2) {
    int i = blockIdx.x * blockDim.x + threadIdx.x;
    if (i >= n2) return;
    float2 v = ((const float2*)left)[i];
    left16[i] = (unsigned)f2bf(v.x) | ((unsigned)f2bf(v.y) << 16);
}

// K1: bcur[b] = b*slot
__global__ void init_bcur_kernel(int* __restrict__ bcur, int nb, int slot) {
    int t = threadIdx.x;
    if (t < nb) bcur[t] = t * slot;
}

// K2: partition edges into slack-slotted buckets (LDS-staged coalesced
// writes) + total = sum(w). Proven 89us (round 9). nb <= 256.
// bsorted[i] = ((row_local<<COLBITS)|col, bits(w)), bucket-contiguous runs.
__global__ __launch_bounds__(256) void partition_kernel(
    const int2* __restrict__ eidx, const float* __restrict__ w, int n_edges,
    int* __restrict__ bcursor, int2* __restrict__ bsorted,
    float* __restrict__ total) {
    __shared__ int lh[256];
    __shared__ int lo[256];
    __shared__ int go[256];
    __shared__ int lcur[256];
    __shared__ int2 stage[CHUNK];
    __shared__ int dstg[CHUNK];
    int t = threadIdx.x;
    int base = blockIdx.x * CHUNK;
    int cnt = min(CHUNK, n_edges - base);

    lh[t] = 0;
    __syncthreads();
    #pragma unroll
    for (int k = 0; k < CHUNK / 256; ++k) {
        int e = base + t + k * 256;
        if (e < n_edges) atomicAdd(&lh[eidx[e].x >> BSHIFT], 1);
    }
    __syncthreads();
    int v = lh[t];
    lo[t] = v;
    __syncthreads();
    for (int off = 1; off < 256; off <<= 1) {
        int u = (t >= off) ? lo[t - off] : 0;
        __syncthreads();
        lo[t] += u;
        __syncthreads();
    }
    int excl = lo[t] - v;
    go[t] = (v > 0) ? atomicAdd(&bcursor[t], v) : 0;
    __syncthreads();
    lo[t] = excl;
    lcur[t] = excl;
    __syncthreads();

    float s = 0.f;
    #pragma unroll
    for (int k = 0; k < CHUNK / 256; ++k) {
        int e = base + t + k * 256;
        if (e < n_edges) {
            int2 rc = eidx[e];
            float wv = w[e];
            s += wv;
            int b = rc.x >> BSHIFT;
            unsigned rl = (unsigned)(rc.x & (BROWS - 1));
            int p = atomicAdd(&lcur[b], 1);
            stage[p] = make_int2((int)((rl << COLBITS) | (unsigned)rc.y),
                                 __float_as_int(wv));
            dstg[p] = go[b] + (p - lo[b]);
        }
    }
    #pragma unroll
    for (int off = 32; off > 0; off >>= 1) s += __shfl_down(s, off, 64);
    if ((t & 63) == 0) atomicAdd(total, s);
    __syncthreads();
    #pragma unroll
    for (int k = 0; k < CHUNK / 256; ++k) {
        int s2 = t + k * 256;
        if (s2 < cnt) bsorted[dstg[s2]] = stage[s2];
    }
}

// K3: bucket accumulate. One block (1024 thr, 16 waves) per bucket;
// 128KB dynamic LDS acc[BROWS][EMB]. Per wave: 8 edges in flight
// (lane = sub*8 + d8, uint4 gather = 8 bf16 dims) + depth-1 payload
// prefetch; 1 ds_add wave-op per edge (2-way banks = free). Epilogue
// writes h = right + t1*(c - conv/total) directly. Replaces rowsort +
// seg_gather.
__global__ __launch_bounds__(1024) void bucket_accum_kernel(
    const int2* __restrict__ bsorted, const int* __restrict__ bcur,
    const uint4* __restrict__ left16o,
    const float* __restrict__ right, const float* __restrict__ c,
    const float* __restrict__ temp, const float* __restrict__ total,
    float* __restrict__ hout, int n_right, int slot) {
    extern __shared__ float acc[];   // BROWS*EMB floats = 128KB
    int b = blockIdx.x;
    int t = threadIdx.x;
    int lane = t & 63;
    int wv = t >> 6;                 // wave 0..15

    float4* a4 = (float4*)acc;
    #pragma unroll
    for (int i = t; i < BROWS * EMB / 4; i += 1024)
        a4[i] = make_float4(0.f, 0.f, 0.f, 0.f);
    __syncthreads();

    int start = b * slot;
    int end = min(bcur[b], start + slot);
    int sub = lane >> 3;             // edge within octet
    int d8 = lane & 7;               // dim octet

    int g0 = start + wv * 8;
    if (g0 < end) {
        int ee = g0 + sub;
        int2 sv = bsorted[(ee < end) ? ee : (end - 1)];
        for (int base = g0; base < end; base += 16 * 8) {
            int2 cur = sv;
            int nb_ = base + 16 * 8;
            if (nb_ < end) {
                int en = nb_ + sub;
                sv = bsorted[(en < end) ? en : (end - 1)];
            }
            int ecur = base + sub;
            float ww = (ecur < end) ? __int_as_float(cur.y) : 0.f;
            unsigned key = (unsigned)cur.x;
            unsigned col = key & COLMASK;
            unsigned rl = key >> COLBITS;
            uint4 pk = left16o[(size_t)col * 8 + d8];
            float* ap = &acc[rl * EMB + d8 * 8];
            atomicAdd(&ap[0], ww * __uint_as_float(pk.x << 16));
            atomicAdd(&ap[1], ww * __uint_as_float(pk.x & 0xffff0000u));
            atomicAdd(&ap[2], ww * __uint_as_float(pk.y << 16));
            atomicAdd(&ap[3], ww * __uint_as_float(pk.y & 0xffff0000u));
            atomicAdd(&ap[4], ww * __uint_as_float(pk.z << 16));
            atomicAdd(&ap[5], ww * __uint_as_float(pk.z & 0xffff0000u));
            atomicAdd(&ap[6], ww * __uint_as_float(pk.w << 16));
            atomicAdd(&ap[7], ww * __uint_as_float(pk.w & 0xffff0000u));
        }
    }
    __syncthreads();

    float inv = 1.0f / fmaxf(total[0], 1.0f);
    float t1 = temp[1];
    int row0 = b << BSHIFT;
    for (int rl = wv; rl < BROWS; rl += 16) {
        int gr = row0 + rl;
        if (gr < n_right) {
            float conv = acc[rl * EMB + lane] * inv;
            hout[(size_t)gr * EMB + lane] =
                right[(size_t)gr * EMB + lane] + t1 * (c[gr] - conv);
        }
    }
}

// K4: tiled MLP (proven round 9).
__global__ __launch_bounds__(256, 4) void mlp_kernel(
    const float* __restrict__ W1, const float* __restrict__ b1,
    const float* __restrict__ W2, const float* __restrict__ b2,
    float* __restrict__ io, int n) {
    __shared__ float hT[64 * HPAD];
    __shared__ float h1T[64 * 64];
    int t = threadIdx.x;
    int r = t & 63;
    int q = __builtin_amdgcn_readfirstlane(t >> 6);
    int row0 = blockIdx.x * MROWS;

    #pragma unroll
    for (int i = 0; i < 16; ++i) {
        int rr = i * 4 + q;
        int gr = row0 + rr;
        float v = (gr < n) ? io[(size_t)gr * EMB + r] : 0.f;
        hT[r * HPAD + rr] = v;
    }
    __syncthreads();

    float acc[16];
    #pragma unroll
    for (int jj = 0; jj < 16; ++jj) acc[jj] = b1[q * 16 + jj];
    for (int k = 0; k < 64; ++k) {
        float hk = hT[k * HPAD + r];
        #pragma unroll
        for (int jj = 0; jj < 16; ++jj)
            acc[jj] = fmaf(hk, W1[(q * 16 + jj) * EMB + k], acc[jj]);
    }
    #pragma unroll
    for (int jj = 0; jj < 16; ++jj)
        h1T[(q * 16 + jj) * 64 + r] = fmaxf(acc[jj], 0.f);
    __syncthreads();

    #pragma unroll
    for (int jj = 0; jj < 16; ++jj) acc[jj] = b2[q * 16 + jj];
    for (int k = 0; k < 64; ++k) {
        float hk = h1T[k * 64 + r];
        #pragma unroll
        for (int jj = 0; jj < 16; ++jj)
            acc[jj] = fmaf(hk, W2[(q * 16 + jj) * EMB + k], acc[jj]);
    }
    __syncthreads();
    #pragma unroll
    for (int jj = 0; jj < 16; ++jj)
        hT[(q * 16 + jj) * HPAD + r] = acc[jj];
    __syncthreads();

    #pragma unroll
    for (int i = 0; i < 16; ++i) {
        int rr = i * 4 + q;
        int gr = row0 + rr;
        if (gr < n) io[(size_t)gr * EMB + r] = hT[r * HPAD + rr];
    }
}

// ===================== mid-path kernels (row-level hist + scans) ==========

__global__ void hist_total_kernel(const int2* __restrict__ eidx,
                                  const float* __restrict__ w, int n_edges,
                                  int* __restrict__ counts,
                                  float* __restrict__ total) {
    int gid = blockIdx.x * blockDim.x + threadIdx.x;
    int stride = gridDim.x * blockDim.x;
    float s = 0.f;
    for (int e = gid; e < n_edges; e += stride) {
        s += w[e];
        atomicAdd(&counts[eidx[e].x], 1);
    }
    #pragma unroll
    for (int off = 32; off > 0; off >>= 1) s += __shfl_down(s, off, 64);
    if ((threadIdx.x & 63) == 0) atomicAdd(total, s);
}

__global__ __launch_bounds__(1024, 1) void scan1_kernel(
    const int* __restrict__ cnt, int* __restrict__ incl,
    int* __restrict__ bsums, int n) {
    __shared__ int s[1024];
    int t = threadIdx.x;
    int i = blockIdx.x * 1024 + t;
    int v = (i < n) ? cnt[i] : 0;
    s[t] = v;
    __syncthreads();
    for (int off = 1; off < 1024; off <<= 1) {
        int u = (t >= off) ? s[t - off] : 0;
        __syncthreads();
        s[t] += u;
        __syncthreads();
    }
    if (i < n) incl[i] = s[t];
    if (t == 1023) bsums[blockIdx.x] = s[t];
}

__global__ __launch_bounds__(256, 1) void scan2_kernel(int* __restrict__ bsums, int nb) {
    __shared__ int s[256];
    int t = threadIdx.x;
    int v = (t < nb) ? bsums[t] : 0;
    s[t] = v;
    __syncthreads();
    for (int off = 1; off < 256; off <<= 1) {
        int u = (t >= off) ? s[t - off] : 0;
        __syncthreads();
        s[t] += u;
        __syncthreads();
    }
    if (t < nb) bsums[t] = s[t] - v;
}

__global__ void scan3_kernel(const int* __restrict__ incl,
                             const int* __restrict__ base,
                             int* __restrict__ offs, int n) {
    int i = blockIdx.x * blockDim.x + threadIdx.x;
    if (i >= n) return;
    offs[i] = (i == 0) ? 0 : incl[i - 1] + base[(i - 1) >> 10];
}

__global__ void scatter_kernel(const int2* __restrict__ eidx,
                               const float* __restrict__ w, int n_edges,
                               int* __restrict__ offs,
                               int2* __restrict__ sorted) {
    int gid = blockIdx.x * blockDim.x + threadIdx.x;
    int stride = gridDim.x * blockDim.x;
    for (int e = gid; e < n_edges; e += stride) {
        int2 rc = eidx[e];
        float v = w[e];
        int pos = atomicAdd(&offs[rc.x], 1);
        sorted[pos] = make_int2(rc.y, __float_as_int(v));
    }
}

// mid path gather (offs are ENDS after scatter); col not masked (no pack)
__global__ void seg_gather_bf16_kernel(const int2* __restrict__ sorted,
                                       const int* __restrict__ offs,
                                       const uint4* __restrict__ left16o,
                                       const float* __restrict__ right,
                                       const float* __restrict__ c,
                                       const float* __restrict__ temp,
                                       const float* __restrict__ total,
                                       float* __restrict__ hout, int n_right,
                                       int n_edges) {
    int gid = blockIdx.x * blockDim.x + threadIdx.x;
    int wid = gid >> 6;
    int lane = gid & 63;
    if (wid >= n_right) return;
    int end = offs[wid];
    int start = (wid == 0) ? 0 : offs[wid - 1];

    int sub = lane >> 3;
    int d8 = lane & 7;
    float cv = c[wid];
    float inv = 1.0f / fmaxf(total[0], 1.0f);
    float t1 = temp[1];

    float a0 = 0.f, a1 = 0.f, a2 = 0.f, a3 = 0.f;
    float a4 = 0.f, a5 = 0.f, a6 = 0.f, a7 = 0.f;

    if (start < end) {
        int ee = start + sub;
        int2 sv = sorted[(ee < end) ? ee : (end - 1)];
        for (int base = start; base < end; base += 8) {
            int2 cur = sv;
            int bnext = base + 8;
            if (bnext < end) {
                int en = bnext + sub;
                sv = sorted[(en < end) ? en : (end - 1)];
            }
            int ecur = base + sub;
            float ww = (ecur < end) ? __int_as_float(cur.y) : 0.f;
            unsigned col = (unsigned)cur.x;
            uint4 pk = left16o[(size_t)col * 8 + d8];
            a0 = fmaf(ww, __uint_as_float(pk.x << 16), a0);
            a1 = fmaf(ww, __uint_as_float(pk.x & 0xffff0000u), a1);
            a2 = fmaf(ww, __uint_as_float(pk.y << 16), a2);
            a3 = fmaf(ww, __uint_as_float(pk.y & 0xffff0000u), a3);
            a4 = fmaf(ww, __uint_as_float(pk.z << 16), a4);
            a5 = fmaf(ww, __uint_as_float(pk.z & 0xffff0000u), a5);
            a6 = fmaf(ww, __uint_as_float(pk.w << 16), a6);
            a7 = fmaf(ww, __uint_as_float(pk.w & 0xffff0000u), a7);
        }
    }

    #define RED8(x) x += __shfl_xor(x, 8, 64); x += __shfl_xor(x, 16, 64); \
                    x += __shfl_xor(x, 32, 64);
    RED8(a0) RED8(a1) RED8(a2) RED8(a3) RED8(a4) RED8(a5) RED8(a6) RED8(a7)
    #undef RED8

    if (lane < 8) {
        const float4* rp = (const float4*)(right + (size_t)wid * EMB);
        float4 r0 = rp[2 * lane];
        float4 r1 = rp[2 * lane + 1];
        float4 h0, h1;
        h0.x = r0.x + t1 * (cv - a0 * inv);
        h0.y = r0.y + t1 * (cv - a1 * inv);
        h0.z = r0.z + t1 * (cv - a2 * inv);
        h0.w = r0.w + t1 * (cv - a3 * inv);
        h1.x = r1.x + t1 * (cv - a4 * inv);
        h1.y = r1.y + t1 * (cv - a5 * inv);
        h1.z = r1.z + t1 * (cv - a6 * inv);
        h1.w = r1.w + t1 * (cv - a7 * inv);
        float4* op = (float4*)(hout + (size_t)wid * EMB);
        op[2 * lane] = h0;
        op[2 * lane + 1] = h1;
    }
}

// ===================== fallback (atomic path) =====================

__global__ void sum_weights_kernel(const float* __restrict__ w, int n,
                                   float* __restrict__ total) {
    int gid = blockIdx.x * blockDim.x + threadIdx.x;
    int stride = gridDim.x * blockDim.x;
    float s = 0.f;
    for (int i = gid; i < n; i += stride) s += w[i];
    #pragma unroll
    for (int off = 32; off > 0; off >>= 1) s += __shfl_down(s, off, 64);
    if ((threadIdx.x & 63) == 0) atomicAdd(total, s);
}

__global__ void edge_scatter_kernel(const int* __restrict__ idx,
                                    const float* __restrict__ w,
                                    const float* __restrict__ left,
                                    const float* __restrict__ total,
                                    float* __restrict__ conv,
                                    long long n_threads) {
    long long gid = (long long)blockIdx.x * blockDim.x + threadIdx.x;
    if (gid >= n_threads) return;
    int e = (int)(gid >> 6);
    int d = (int)(gid & 63);
    float inv = 1.0f / fmaxf(total[0], 1.0f);
    int row = idx[2 * e];
    int col = idx[2 * e + 1];
    float v = w[e] * inv;
    float msg = left[(size_t)col * EMB + d] * v;
    atomicAdd(&conv[(size_t)row * EMB + d], msg);
}

__global__ __launch_bounds__(256, 1) void fused_mlp_kernel(
    const float* __restrict__ right, const float* __restrict__ c,
    const float* __restrict__ temp,
    const float* __restrict__ W1, const float* __restrict__ b1,
    const float* __restrict__ W2, const float* __restrict__ b2,
    float* __restrict__ io, int n) {
    int r = blockIdx.x * blockDim.x + threadIdx.x;
    if (r >= n) return;
    float t1 = temp[1];
    float cv = c[r];
    float h[EMB];
    const float4* rp = (const float4*)(right + (size_t)r * EMB);
    const float4* qp = (const float4*)(io + (size_t)r * EMB);
    #pragma unroll
    for (int qq = 0; qq < EMB / 4; ++qq) {
        float4 rv = rp[qq];
        float4 qv = qp[qq];
        h[4 * qq + 0] = rv.x + t1 * (cv - qv.x);
        h[4 * qq + 1] = rv.y + t1 * (cv - qv.y);
        h[4 * qq + 2] = rv.z + t1 * (cv - qv.z);
        h[4 * qq + 3] = rv.w + t1 * (cv - qv.w);
    }
    float h1[EMB];
    #pragma unroll
    for (int j = 0; j < EMB; j += 4) {
        float s0 = b1[j], s1 = b1[j + 1], s2 = b1[j + 2], s3 = b1[j + 3];
        #pragma unroll
        for (int k = 0; k < EMB; ++k) {
            float hk = h[k];
            s0 = fmaf(hk, W1[(j + 0) * EMB + k], s0);
            s1 = fmaf(hk, W1[(j + 1) * EMB + k], s1);
            s2 = fmaf(hk, W1[(j + 2) * EMB + k], s2);
            s3 = fmaf(hk, W1[(j + 3) * EMB + k], s3);
        }
        h1[j] = fmaxf(s0, 0.f);
        h1[j + 1] = fmaxf(s1, 0.f);
        h1[j + 2] = fmaxf(s2, 0.f);
        h1[j + 3] = fmaxf(s3, 0.f);
    }
    float4* op = (float4*)(io + (size_t)r * EMB);
    #pragma unroll
    for (int j = 0; j < EMB; j += 4) {
        float s0 = b2[j], s1 = b2[j + 1], s2 = b2[j + 2], s3 = b2[j + 3];
        #pragma unroll
        for (int k = 0; k < EMB; ++k) {
            float hk = h1[k];
            s0 = fmaf(hk, W2[(j + 0) * EMB + k], s0);
            s1 = fmaf(hk, W2[(j + 1) * EMB + k], s1);
            s2 = fmaf(hk, W2[(j + 2) * EMB + k], s2);
            s3 = fmaf(hk, W2[(j + 3) * EMB + k], s3);
        }
        op[j / 4] = make_float4(s0, s1, s2, s3);
    }
}

// ===================== launch =====================

extern "C" void kernel_launch(void* const* d_in, const int* in_sizes, int n_in,
                              void* d_out, int out_size, void* d_ws, size_t ws_size,
                              hipStream_t stream) {
    const float* left   = (const float*)d_in[0];
    const int*   eidx   = (const int*)d_in[2];
    const float* ew     = (const float*)d_in[3];
    const float* right  = (const float*)d_in[4];
    const float* c      = (const float*)d_in[5];
    const float* temp   = (const float*)d_in[7];
    const float* W1     = (const float*)d_in[8];
    const float* b1     = (const float*)d_in[9];
    const float* W2     = (const float*)d_in[10];
    const float* b2     = (const float*)d_in[11];

    const int n_edges = in_sizes[3];
    const int n_right = in_sizes[4] / EMB;
    const int n_left  = in_sizes[0] / EMB;
    float* out = (float*)d_out;

    const int nb = (n_right + BROWS - 1) >> BSHIFT;
    const int nblocks_scan = (n_right + 1023) / 1024;

    auto align256 = [](size_t x) { return (x + 255) & ~(size_t)255; };

    int slot = n_edges / (nb > 0 ? nb : 1);
    slot += slot / 16 + 128;

    // full path: total | bcur(nb) | bsorted(nb*slot + slot) | left16
    size_t off_bcur    = 64;
    size_t off_bsorted = align256(off_bcur + (size_t)nb * 4);
    size_t off_left16f = align256(off_bsorted + ((size_t)nb * slot + slot) * 8);
    size_t req_full    = off_left16f + (size_t)n_left * EMB * 2;

    // mid path: total | offs | incl | bsum | sorted | left16
    size_t m_off_offs   = 64;
    size_t m_off_incl   = align256(m_off_offs + (size_t)n_right * 4);
    size_t m_off_bsum   = align256(m_off_incl + (size_t)n_right * 4);
    size_t m_off_sorted = align256(m_off_bsum + 1024);
    size_t m_off_left16 = align256(m_off_sorted + (size_t)n_edges * 8);
    size_t req_mid      = m_off_left16 + (size_t)n_left * EMB * 2;

    bool common_ok = (nb <= 256) && (nblocks_scan <= 256) &&
                     (n_left <= (1 << COLBITS)) && (BROWS * nb >= n_right);

    if (common_ok && ws_size >= req_full) {
        // ---------- full path: partition + bucket LDS accumulate ----------
        char* ws = (char*)d_ws;
        float* total = (float*)ws;
        int* bcur = (int*)(ws + off_bcur);
        int2* bsorted = (int2*)(ws + off_bsorted);
        unsigned short* left16 = (unsigned short*)(ws + off_left16f);

        hipMemsetAsync(ws, 0, 64, stream);  // total

        int n2 = n_left * EMB / 2;
        convert_left_kernel<<<(n2 + 255) / 256, 256, 0, stream>>>(
            left, (unsigned*)left16, n2);
        init_bcur_kernel<<<1, 256, 0, stream>>>(bcur, nb, slot);
        {
            int nchunks = (n_edges + CHUNK - 1) / CHUNK;
            partition_kernel<<<nchunks, 256, 0, stream>>>(
                (const int2*)eidx, ew, n_edges, bcur, bsorted, total);
        }
        bucket_accum_kernel<<<nb, 1024, BROWS * EMB * 4, stream>>>(
            bsorted, bcur, (const uint4*)left16, right, c, temp, total,
            out, n_right, slot);
        mlp_kernel<<<(n_right + MROWS - 1) / MROWS, 256, 0, stream>>>(
            W1, b1, W2, b2, out, n_right);
    } else if (common_ok && ws_size >= req_mid) {
        // ---------- mid path: row-sort + seg_gather ----------
        char* ws = (char*)d_ws;
        float* total = (float*)ws;
        int* offs = (int*)(ws + m_off_offs);
        int* incl = (int*)(ws + m_off_incl);
        int* bsum = (int*)(ws + m_off_bsum);
        int2* sorted = (int2*)(ws + m_off_sorted);
        unsigned short* left16 = (unsigned short*)(ws + m_off_left16);

        hipMemsetAsync(ws, 0, m_off_offs + (size_t)n_right * 4, stream);

        int n2 = n_left * EMB / 2;
        convert_left_kernel<<<(n2 + 255) / 256, 256, 0, stream>>>(
            left, (unsigned*)left16, n2);
        hist_total_kernel<<<2048, 256, 0, stream>>>((const int2*)eidx, ew,
                                                    n_edges, offs, total);
        scan1_kernel<<<nblocks_scan, 1024, 0, stream>>>(offs, incl, bsum, n_right);
        scan2_kernel<<<1, 256, 0, stream>>>(bsum, nblocks_scan);
        scan3_kernel<<<(n_right + 255) / 256, 256, 0, stream>>>(incl, bsum, offs,
                                                                n_right);
        scatter_kernel<<<2048, 256, 0, stream>>>((const int2*)eidx, ew, n_edges,
                                                 offs, sorted);
        {
            long long n_threads = (long long)n_right * EMB;
            int blocks = (int)((n_threads + 255) / 256);
            seg_gather_bf16_kernel<<<blocks, 256, 0, stream>>>(
                sorted, offs, (const uint4*)left16, right, c, temp, total,
                out, n_right, n_edges);
        }
        mlp_kernel<<<(n_right + MROWS - 1) / MROWS, 256, 0, stream>>>(
            W1, b1, W2, b2, out, n_right);
    } else {
        // ---------- fallback: atomic path ----------
        float* total = (float*)d_ws;
        hipMemsetAsync(d_out, 0, (size_t)out_size * sizeof(float), stream);
        hipMemsetAsync(d_ws, 0, sizeof(float), stream);
        sum_weights_kernel<<<2048, 256, 0, stream>>>(ew, n_edges, total);
        long long n_threads = (long long)n_edges * EMB;
        long long blocks = (n_threads + 255) / 256;
        edge_scatter_kernel<<<(int)blocks, 256, 0, stream>>>(
            eidx, ew, left, total, out, n_threads);
        int mblocks = (n_right + 255) / 256;
        fused_mlp_kernel<<<mblocks, 256, 0, stream>>>(right, c, temp, W1, b1, W2,
                                                      b2, out, n_right);
    }
}

// Round 12
// 341.353 us; speedup vs baseline: 4.4002x; 4.4002x over previous
//
#include <hip/hip_runtime.h>

#define EMB 64
#define BROWS 512            // rows per bucket
#define BSHIFT 9             // log2(BROWS)
#define CHUNK 4096           // edges per partition block
#define COLBITS 23
#define COLMASK ((1u << COLBITS) - 1u)
#define MROWS 64             // rows per MLP block
#define HPAD 66              // padded stride for hT

// bf16 pack (RNE)
__device__ __forceinline__ unsigned short f2bf(float f) {
    unsigned u = __float_as_uint(f);
    u = u + 0x7FFFu + ((u >> 16) & 1u);
    return (unsigned short)(u >> 16);
}

// K0: convert left (f32) -> left16 (bf16), 2 elems/thread
__global__ void convert_left_kernel(const float* __restrict__ left,
                                    unsigned* __restrict__ left16, int n2) {
    int i = blockIdx.x * blockDim.x + threadIdx.x;
    if (i >= n2) return;
    float2 v = ((const float2*)left)[i];
    left16[i] = (unsigned)f2bf(v.x) | ((unsigned)f2bf(v.y) << 16);
}

// K1: bcur[b] = b*slot
__global__ void init_bcur_kernel(int* __restrict__ bcur, int nb, int slot) {
    int t = threadIdx.x;
    if (t < nb) bcur[t] = t * slot;
}

// K2: partition edges into slack-slotted buckets (LDS-staged coalesced
// writes) + total = sum(w). 1024 threads (4 edges/thread) for occupancy;
// LDS-atomic floor ~200cy per wave-op is per-lane-serialized [r4/r11 model].
// bsorted[i] = ((row_local<<COLBITS)|col, bits(w)), bucket-contiguous runs.
__global__ __launch_bounds__(1024, 8) void partition_kernel(
    const int2* __restrict__ eidx, const float* __restrict__ w, int n_edges,
    int* __restrict__ bcursor, int2* __restrict__ bsorted,
    float* __restrict__ total) {
    __shared__ int lh[256];
    __shared__ int lo[256];
    __shared__ int go[256];
    __shared__ int lcur[256];
    __shared__ int2 stage[CHUNK];
    __shared__ int dstg[CHUNK];
    int t = threadIdx.x;
    int base = blockIdx.x * CHUNK;
    int cnt = min(CHUNK, n_edges - base);

    if (t < 256) lh[t] = 0;
    __syncthreads();
    #pragma unroll
    for (int k = 0; k < CHUNK / 1024; ++k) {
        int e = base + t + k * 1024;
        if (e < n_edges) atomicAdd(&lh[eidx[e].x >> BSHIFT], 1);
    }
    __syncthreads();
    int v = (t < 256) ? lh[t] : 0;
    if (t < 256) lo[t] = v;
    __syncthreads();
    for (int off = 1; off < 256; off <<= 1) {
        int u = (t < 256 && t >= off) ? lo[t - off] : 0;
        __syncthreads();
        if (t < 256) lo[t] += u;
        __syncthreads();
    }
    if (t < 256) {
        int excl = lo[t] - v;
        go[t] = (v > 0) ? atomicAdd(&bcursor[t], v) : 0;
        lo[t] = excl;
        lcur[t] = excl;
    }
    __syncthreads();

    float s = 0.f;
    #pragma unroll
    for (int k = 0; k < CHUNK / 1024; ++k) {
        int e = base + t + k * 1024;
        if (e < n_edges) {
            int2 rc = eidx[e];
            float wv = w[e];
            s += wv;
            int b = rc.x >> BSHIFT;
            unsigned rl = (unsigned)(rc.x & (BROWS - 1));
            int p = atomicAdd(&lcur[b], 1);
            stage[p] = make_int2((int)((rl << COLBITS) | (unsigned)rc.y),
                                 __float_as_int(wv));
            dstg[p] = go[b] + (p - lo[b]);
        }
    }
    #pragma unroll
    for (int off = 32; off > 0; off >>= 1) s += __shfl_down(s, off, 64);
    if ((t & 63) == 0) atomicAdd(total, s);
    __syncthreads();
    #pragma unroll
    for (int k = 0; k < CHUNK / 1024; ++k) {
        int s2 = t + k * 1024;
        if (s2 < cnt) bsorted[dstg[s2]] = stage[s2];
    }
}

// K3: dense bases: sbase[b] = exclusive scan of (bcur[b] - b*slot)
__global__ __launch_bounds__(256, 1) void count_scan_kernel(
    const int* __restrict__ bcur, int* __restrict__ sbase, int nb, int slot) {
    __shared__ int ssc[256];
    int t = threadIdx.x;
    int cnt = (t < nb) ? (bcur[t] - t * slot) : 0;
    ssc[t] = cnt;
    __syncthreads();
    for (int off = 1; off < 256; off <<= 1) {
        int u = (t >= off) ? ssc[t - off] : 0;
        __syncthreads();
        ssc[t] += u;
        __syncthreads();
    }
    if (t < nb) sbase[t] = ssc[t] - cnt;
}

// K4: one block (1024 thr) per bucket: per-row offsets in LDS + L2-local
// row scatter into DENSE sorted2; writes dense offs[row] starts.
__global__ __launch_bounds__(1024) void local_rowsort_kernel(
    const int2* __restrict__ bsorted, const int* __restrict__ bcur,
    const int* __restrict__ sbase, int* __restrict__ offs,
    int2* __restrict__ sorted2, int n_right, int slot) {
    __shared__ int lhist[BROWS];
    __shared__ int lcur[BROWS];
    __shared__ int ps[BROWS];
    int b = blockIdx.x;
    int t = threadIdx.x;
    int src0 = b * slot;
    int send = min(bcur[b], src0 + slot);
    int dbase = sbase[b];
    int row0 = b << BSHIFT;
    int nrows = min(BROWS, n_right - row0);

    if (t < BROWS) lhist[t] = 0;
    __syncthreads();
    for (int e = src0 + t; e < send; e += 1024)
        atomicAdd(&lhist[((unsigned)bsorted[e].x) >> COLBITS], 1);
    __syncthreads();

    if (t < BROWS) ps[t] = lhist[t];
    __syncthreads();
    for (int off = 1; off < BROWS; off <<= 1) {
        int u = (t < BROWS && t >= off) ? ps[t - off] : 0;
        __syncthreads();
        if (t < BROWS) ps[t] += u;
        __syncthreads();
    }
    if (t < BROWS) {
        int excl = ps[t] - lhist[t];
        lcur[t] = excl;
        if (t < nrows) offs[row0 + t] = dbase + excl;
    }
    __syncthreads();

    int e = src0 + t;
    for (; e + 3 * 1024 < send; e += 4 * 1024) {
        int2 e0 = bsorted[e + 0 * 1024];
        int2 e1 = bsorted[e + 1 * 1024];
        int2 e2 = bsorted[e + 2 * 1024];
        int2 e3 = bsorted[e + 3 * 1024];
        int p0 = atomicAdd(&lcur[((unsigned)e0.x) >> COLBITS], 1);
        int p1 = atomicAdd(&lcur[((unsigned)e1.x) >> COLBITS], 1);
        int p2 = atomicAdd(&lcur[((unsigned)e2.x) >> COLBITS], 1);
        int p3 = atomicAdd(&lcur[((unsigned)e3.x) >> COLBITS], 1);
        sorted2[dbase + p0] = e0;
        sorted2[dbase + p1] = e1;
        sorted2[dbase + p2] = e2;
        sorted2[dbase + p3] = e3;
    }
    for (; e < send; e += 1024) {
        int2 e0 = bsorted[e];
        int p0 = atomicAdd(&lcur[((unsigned)e0.x) >> COLBITS], 1);
        sorted2[dbase + p0] = e0;
    }
}

// K5: one wave per row, 8 edges per iteration, depth-1 sorted prefetch.
__global__ void seg_gather_bf16_kernel(const int2* __restrict__ sorted,
                                       const int* __restrict__ offs,
                                       const uint4* __restrict__ left16o,
                                       const float* __restrict__ right,
                                       const float* __restrict__ c,
                                       const float* __restrict__ temp,
                                       const float* __restrict__ total,
                                       float* __restrict__ hout, int n_right,
                                       int n_edges, int offs_are_ends) {
    int gid = blockIdx.x * blockDim.x + threadIdx.x;
    int wid = gid >> 6;
    int lane = gid & 63;
    if (wid >= n_right) return;
    int start, end;
    if (offs_are_ends) {
        end = offs[wid];
        start = (wid == 0) ? 0 : offs[wid - 1];
    } else {
        start = offs[wid];
        end = (wid + 1 < n_right) ? offs[wid + 1] : n_edges;
    }

    int sub = lane >> 3;       // edge within octet
    int d8  = lane & 7;        // dim octet

    float cv = c[wid];
    float inv = 1.0f / fmaxf(total[0], 1.0f);
    float t1 = temp[1];

    float a0 = 0.f, a1 = 0.f, a2 = 0.f, a3 = 0.f;
    float a4 = 0.f, a5 = 0.f, a6 = 0.f, a7 = 0.f;

    if (start < end) {
        int ee = start + sub;
        int2 sv = sorted[(ee < end) ? ee : (end - 1)];
        for (int base = start; base < end; base += 8) {
            int2 cur = sv;
            int ecur = base + sub;
            int bnext = base + 8;
            if (bnext < end) {
                int en = bnext + sub;
                sv = sorted[(en < end) ? en : (end - 1)];
            }
            float wv = (ecur < end) ? __int_as_float(cur.y) : 0.f;
            unsigned col = (unsigned)cur.x & COLMASK;
            uint4 pk = left16o[(size_t)col * 8 + d8];
            a0 = fmaf(wv, __uint_as_float(pk.x << 16), a0);
            a1 = fmaf(wv, __uint_as_float(pk.x & 0xffff0000u), a1);
            a2 = fmaf(wv, __uint_as_float(pk.y << 16), a2);
            a3 = fmaf(wv, __uint_as_float(pk.y & 0xffff0000u), a3);
            a4 = fmaf(wv, __uint_as_float(pk.z << 16), a4);
            a5 = fmaf(wv, __uint_as_float(pk.z & 0xffff0000u), a5);
            a6 = fmaf(wv, __uint_as_float(pk.w << 16), a6);
            a7 = fmaf(wv, __uint_as_float(pk.w & 0xffff0000u), a7);
        }
    }

    #define RED8(x) x += __shfl_xor(x, 8, 64); x += __shfl_xor(x, 16, 64); \
                    x += __shfl_xor(x, 32, 64);
    RED8(a0) RED8(a1) RED8(a2) RED8(a3) RED8(a4) RED8(a5) RED8(a6) RED8(a7)
    #undef RED8

    if (lane < 8) {
        const float4* rp = (const float4*)(right + (size_t)wid * EMB);
        float4 r0 = rp[2 * lane];
        float4 r1 = rp[2 * lane + 1];
        float4 h0, h1;
        h0.x = r0.x + t1 * (cv - a0 * inv);
        h0.y = r0.y + t1 * (cv - a1 * inv);
        h0.z = r0.z + t1 * (cv - a2 * inv);
        h0.w = r0.w + t1 * (cv - a3 * inv);
        h1.x = r1.x + t1 * (cv - a4 * inv);
        h1.y = r1.y + t1 * (cv - a5 * inv);
        h1.z = r1.z + t1 * (cv - a6 * inv);
        h1.w = r1.w + t1 * (cv - a7 * inv);
        float4* op = (float4*)(hout + (size_t)wid * EMB);
        op[2 * lane] = h0;
        op[2 * lane + 1] = h1;
    }
}

// K6: tiled MLP (proven round 9).
__global__ __launch_bounds__(256, 4) void mlp_kernel(
    const float* __restrict__ W1, const float* __restrict__ b1,
    const float* __restrict__ W2, const float* __restrict__ b2,
    float* __restrict__ io, int n) {
    __shared__ float hT[64 * HPAD];
    __shared__ float h1T[64 * 64];
    int t = threadIdx.x;
    int r = t & 63;
    int q = __builtin_amdgcn_readfirstlane(t >> 6);
    int row0 = blockIdx.x * MROWS;

    #pragma unroll
    for (int i = 0; i < 16; ++i) {
        int rr = i * 4 + q;
        int gr = row0 + rr;
        float v = (gr < n) ? io[(size_t)gr * EMB + r] : 0.f;
        hT[r * HPAD + rr] = v;
    }
    __syncthreads();

    float acc[16];
    #pragma unroll
    for (int jj = 0; jj < 16; ++jj) acc[jj] = b1[q * 16 + jj];
    for (int k = 0; k < 64; ++k) {
        float hk = hT[k * HPAD + r];
        #pragma unroll
        for (int jj = 0; jj < 16; ++jj)
            acc[jj] = fmaf(hk, W1[(q * 16 + jj) * EMB + k], acc[jj]);
    }
    #pragma unroll
    for (int jj = 0; jj < 16; ++jj)
        h1T[(q * 16 + jj) * 64 + r] = fmaxf(acc[jj], 0.f);
    __syncthreads();

    #pragma unroll
    for (int jj = 0; jj < 16; ++jj) acc[jj] = b2[q * 16 + jj];
    for (int k = 0; k < 64; ++k) {
        float hk = h1T[k * 64 + r];
        #pragma unroll
        for (int jj = 0; jj < 16; ++jj)
            acc[jj] = fmaf(hk, W2[(q * 16 + jj) * EMB + k], acc[jj]);
    }
    __syncthreads();
    #pragma unroll
    for (int jj = 0; jj < 16; ++jj)
        hT[(q * 16 + jj) * HPAD + r] = acc[jj];
    __syncthreads();

    #pragma unroll
    for (int i = 0; i < 16; ++i) {
        int rr = i * 4 + q;
        int gr = row0 + rr;
        if (gr < n) io[(size_t)gr * EMB + r] = hT[r * HPAD + rr];
    }
}

// ===================== mid-path kernels (row-level hist + scans) ==========

__global__ void hist_total_kernel(const int2* __restrict__ eidx,
                                  const float* __restrict__ w, int n_edges,
                                  int* __restrict__ counts,
                                  float* __restrict__ total) {
    int gid = blockIdx.x * blockDim.x + threadIdx.x;
    int stride = gridDim.x * blockDim.x;
    float s = 0.f;
    for (int e = gid; e < n_edges; e += stride) {
        s += w[e];
        atomicAdd(&counts[eidx[e].x], 1);
    }
    #pragma unroll
    for (int off = 32; off > 0; off >>= 1) s += __shfl_down(s, off, 64);
    if ((threadIdx.x & 63) == 0) atomicAdd(total, s);
}

__global__ __launch_bounds__(1024, 1) void scan1_kernel(
    const int* __restrict__ cnt, int* __restrict__ incl,
    int* __restrict__ bsums, int n) {
    __shared__ int s[1024];
    int t = threadIdx.x;
    int i = blockIdx.x * 1024 + t;
    int v = (i < n) ? cnt[i] : 0;
    s[t] = v;
    __syncthreads();
    for (int off = 1; off < 1024; off <<= 1) {
        int u = (t >= off) ? s[t - off] : 0;
        __syncthreads();
        s[t] += u;
        __syncthreads();
    }
    if (i < n) incl[i] = s[t];
    if (t == 1023) bsums[blockIdx.x] = s[t];
}

__global__ __launch_bounds__(256, 1) void scan2_kernel(int* __restrict__ bsums, int nb) {
    __shared__ int s[256];
    int t = threadIdx.x;
    int v = (t < nb) ? bsums[t] : 0;
    s[t] = v;
    __syncthreads();
    for (int off = 1; off < 256; off <<= 1) {
        int u = (t >= off) ? s[t - off] : 0;
        __syncthreads();
        s[t] += u;
        __syncthreads();
    }
    if (t < nb) bsums[t] = s[t] - v;
}

__global__ void scan3_kernel(const int* __restrict__ incl,
                             const int* __restrict__ base,
                             int* __restrict__ offs, int n) {
    int i = blockIdx.x * blockDim.x + threadIdx.x;
    if (i >= n) return;
    offs[i] = (i == 0) ? 0 : incl[i - 1] + base[(i - 1) >> 10];
}

__global__ void scatter_kernel(const int2* __restrict__ eidx,
                               const float* __restrict__ w, int n_edges,
                               int* __restrict__ offs,
                               int2* __restrict__ sorted) {
    int gid = blockIdx.x * blockDim.x + threadIdx.x;
    int stride = gridDim.x * blockDim.x;
    for (int e = gid; e < n_edges; e += stride) {
        int2 rc = eidx[e];
        float v = w[e];
        int pos = atomicAdd(&offs[rc.x], 1);
        sorted[pos] = make_int2(rc.y, __float_as_int(v));
    }
}

// ===================== fallback (atomic path) =====================

__global__ void sum_weights_kernel(const float* __restrict__ w, int n,
                                   float* __restrict__ total) {
    int gid = blockIdx.x * blockDim.x + threadIdx.x;
    int stride = gridDim.x * blockDim.x;
    float s = 0.f;
    for (int i = gid; i < n; i += stride) s += w[i];
    #pragma unroll
    for (int off = 32; off > 0; off >>= 1) s += __shfl_down(s, off, 64);
    if ((threadIdx.x & 63) == 0) atomicAdd(total, s);
}

__global__ void edge_scatter_kernel(const int* __restrict__ idx,
                                    const float* __restrict__ w,
                                    const float* __restrict__ left,
                                    const float* __restrict__ total,
                                    float* __restrict__ conv,
                                    long long n_threads) {
    long long gid = (long long)blockIdx.x * blockDim.x + threadIdx.x;
    if (gid >= n_threads) return;
    int e = (int)(gid >> 6);
    int d = (int)(gid & 63);
    float inv = 1.0f / fmaxf(total[0], 1.0f);
    int row = idx[2 * e];
    int col = idx[2 * e + 1];
    float v = w[e] * inv;
    float msg = left[(size_t)col * EMB + d] * v;
    atomicAdd(&conv[(size_t)row * EMB + d], msg);
}

__global__ __launch_bounds__(256, 1) void fused_mlp_kernel(
    const float* __restrict__ right, const float* __restrict__ c,
    const float* __restrict__ temp,
    const float* __restrict__ W1, const float* __restrict__ b1,
    const float* __restrict__ W2, const float* __restrict__ b2,
    float* __restrict__ io, int n) {
    int r = blockIdx.x * blockDim.x + threadIdx.x;
    if (r >= n) return;
    float t1 = temp[1];
    float cv = c[r];
    float h[EMB];
    const float4* rp = (const float4*)(right + (size_t)r * EMB);
    const float4* qp = (const float4*)(io + (size_t)r * EMB);
    #pragma unroll
    for (int qq = 0; qq < EMB / 4; ++qq) {
        float4 rv = rp[qq];
        float4 qv = qp[qq];
        h[4 * qq + 0] = rv.x + t1 * (cv - qv.x);
        h[4 * qq + 1] = rv.y + t1 * (cv - qv.y);
        h[4 * qq + 2] = rv.z + t1 * (cv - qv.z);
        h[4 * qq + 3] = rv.w + t1 * (cv - qv.w);
    }
    float h1[EMB];
    #pragma unroll
    for (int j = 0; j < EMB; j += 4) {
        float s0 = b1[j], s1 = b1[j + 1], s2 = b1[j + 2], s3 = b1[j + 3];
        #pragma unroll
        for (int k = 0; k < EMB; ++k) {
            float hk = h[k];
            s0 = fmaf(hk, W1[(j + 0) * EMB + k], s0);
            s1 = fmaf(hk, W1[(j + 1) * EMB + k], s1);
            s2 = fmaf(hk, W1[(j + 2) * EMB + k], s2);
            s3 = fmaf(hk, W1[(j + 3) * EMB + k], s3);
        }
        h1[j] = fmaxf(s0, 0.f);
        h1[j + 1] = fmaxf(s1, 0.f);
        h1[j + 2] = fmaxf(s2, 0.f);
        h1[j + 3] = fmaxf(s3, 0.f);
    }
    float4* op = (float4*)(io + (size_t)r * EMB);
    #pragma unroll
    for (int j = 0; j < EMB; j += 4) {
        float s0 = b2[j], s1 = b2[j + 1], s2 = b2[j + 2], s3 = b2[j + 3];
        #pragma unroll
        for (int k = 0; k < EMB; ++k) {
            float hk = h1[k];
            s0 = fmaf(hk, W2[(j + 0) * EMB + k], s0);
            s1 = fmaf(hk, W2[(j + 1) * EMB + k], s1);
            s2 = fmaf(hk, W2[(j + 2) * EMB + k], s2);
            s3 = fmaf(hk, W2[(j + 3) * EMB + k], s3);
        }
        op[j / 4] = make_float4(s0, s1, s2, s3);
    }
}

// ===================== launch =====================

extern "C" void kernel_launch(void* const* d_in, const int* in_sizes, int n_in,
                              void* d_out, int out_size, void* d_ws, size_t ws_size,
                              hipStream_t stream) {
    const float* left   = (const float*)d_in[0];
    const int*   eidx   = (const int*)d_in[2];
    const float* ew     = (const float*)d_in[3];
    const float* right  = (const float*)d_in[4];
    const float* c      = (const float*)d_in[5];
    const float* temp   = (const float*)d_in[7];
    const float* W1     = (const float*)d_in[8];
    const float* b1     = (const float*)d_in[9];
    const float* W2     = (const float*)d_in[10];
    const float* b2     = (const float*)d_in[11];

    const int n_edges = in_sizes[3];
    const int n_right = in_sizes[4] / EMB;
    const int n_left  = in_sizes[0] / EMB;
    float* out = (float*)d_out;

    const int nb = (n_right + BROWS - 1) >> BSHIFT;
    const int nblocks_scan = (n_right + 1023) / 1024;

    auto align256 = [](size_t x) { return (x + 255) & ~(size_t)255; };

    int slot = n_edges / (nb > 0 ? nb : 1);
    slot += slot / 16 + 128;

    size_t off_bcur    = 64;
    size_t off_sbase   = align256(off_bcur + (size_t)nb * 4);
    size_t off_offs    = align256(off_sbase + (size_t)(nb + 1) * 4);
    size_t off_bsorted = align256(off_offs + (size_t)n_right * 4);
    size_t off_sorted2 = align256(off_bsorted + ((size_t)nb * slot + slot) * 8);
    size_t off_left16f = align256(off_sorted2 + (size_t)n_edges * 8);
    size_t req_full    = off_left16f + (size_t)n_left * EMB * 2;

    size_t m_off_offs   = 64;
    size_t m_off_incl   = align256(m_off_offs + (size_t)n_right * 4);
    size_t m_off_bsum   = align256(m_off_incl + (size_t)n_right * 4);
    size_t m_off_sorted = align256(m_off_bsum + 1024);
    size_t m_off_left16 = align256(m_off_sorted + (size_t)n_edges * 8);
    size_t req_mid      = m_off_left16 + (size_t)n_left * EMB * 2;

    bool common_ok = (nb <= 256) && (nblocks_scan <= 256) &&
                     (n_left <= (1 << COLBITS)) && (BROWS * nb >= n_right);

    if (common_ok && ws_size >= req_full) {
        // ---------- full path ----------
        char* ws = (char*)d_ws;
        float* total = (float*)ws;
        int* bcur = (int*)(ws + off_bcur);
        int* sbase = (int*)(ws + off_sbase);
        int* offs = (int*)(ws + off_offs);
        int2* bsorted = (int2*)(ws + off_bsorted);
        int2* sorted2 = (int2*)(ws + off_sorted2);
        unsigned short* left16 = (unsigned short*)(ws + off_left16f);

        hipMemsetAsync(ws, 0, 64, stream);  // total

        int n2 = n_left * EMB / 2;
        convert_left_kernel<<<(n2 + 255) / 256, 256, 0, stream>>>(
            left, (unsigned*)left16, n2);
        init_bcur_kernel<<<1, 256, 0, stream>>>(bcur, nb, slot);
        {
            int nchunks = (n_edges + CHUNK - 1) / CHUNK;
            partition_kernel<<<nchunks, 1024, 0, stream>>>(
                (const int2*)eidx, ew, n_edges, bcur, bsorted, total);
        }
        count_scan_kernel<<<1, 256, 0, stream>>>(bcur, sbase, nb, slot);
        local_rowsort_kernel<<<nb, 1024, 0, stream>>>(bsorted, bcur, sbase, offs,
                                                      sorted2, n_right, slot);
        {
            long long n_threads = (long long)n_right * EMB;
            int blocks = (int)((n_threads + 255) / 256);
            seg_gather_bf16_kernel<<<blocks, 256, 0, stream>>>(
                sorted2, offs, (const uint4*)left16, right, c, temp, total,
                out, n_right, n_edges, 0);
        }
        mlp_kernel<<<(n_right + MROWS - 1) / MROWS, 256, 0, stream>>>(
            W1, b1, W2, b2, out, n_right);
    } else if (common_ok && ws_size >= req_mid) {
        // ---------- mid path ----------
        char* ws = (char*)d_ws;
        float* total = (float*)ws;
        int* offs = (int*)(ws + m_off_offs);
        int* incl = (int*)(ws + m_off_incl);
        int* bsum = (int*)(ws + m_off_bsum);
        int2* sorted = (int2*)(ws + m_off_sorted);
        unsigned short* left16 = (unsigned short*)(ws + m_off_left16);

        hipMemsetAsync(ws, 0, m_off_offs + (size_t)n_right * 4, stream);

        int n2 = n_left * EMB / 2;
        convert_left_kernel<<<(n2 + 255) / 256, 256, 0, stream>>>(
            left, (unsigned*)left16, n2);
        hist_total_kernel<<<2048, 256, 0, stream>>>((const int2*)eidx, ew,
                                                    n_edges, offs, total);
        scan1_kernel<<<nblocks_scan, 1024, 0, stream>>>(offs, incl, bsum, n_right);
        scan2_kernel<<<1, 256, 0, stream>>>(bsum, nblocks_scan);
        scan3_kernel<<<(n_right + 255) / 256, 256, 0, stream>>>(incl, bsum, offs,
                                                                n_right);
        scatter_kernel<<<2048, 256, 0, stream>>>((const int2*)eidx, ew, n_edges,
                                                 offs, sorted);
        {
            long long n_threads = (long long)n_right * EMB;
            int blocks = (int)((n_threads + 255) / 256);
            seg_gather_bf16_kernel<<<blocks, 256, 0, stream>>>(
                sorted, offs, (const uint4*)left16, right, c, temp, total,
                out, n_right, n_edges, 1);
        }
        mlp_kernel<<<(n_right + MROWS - 1) / MROWS, 256, 0, stream>>>(
            W1, b1, W2, b2, out, n_right);
    } else {
        // ---------- fallback: atomic path ----------
        float* total = (float*)d_ws;
        hipMemsetAsync(d_out, 0, (size_t)out_size * sizeof(float), stream);
        hipMemsetAsync(d_ws, 0, sizeof(float), stream);
        sum_weights_kernel<<<2048, 256, 0, stream>>>(ew, n_edges, total);
        long long n_threads = (long long)n_edges * EMB;
        long long blocks = (n_threads + 255) / 256;
        edge_scatter_kernel<<<(int)blocks, 256, 0, stream>>>(
            eidx, ew, left, total, out, n_threads);
        int mblocks = (n_right + 255) / 256;
        fused_mlp_kernel<<<mblocks, 256, 0, stream>>>(right, c, temp, W1, b1, W2,
                                                      b2, out, n_right);
    }
}

// Round 13
// 230.278 us; speedup vs baseline: 6.5227x; 1.4824x over previous
//
#include <hip/hip_runtime.h>

#define EMB 64
#define BROWS 512            // rows per bucket
#define BSHIFT 9             // log2(BROWS)
#define CHUNK 4096           // edges per partition block
#define COLBITS 23
#define COLMASK ((1u << COLBITS) - 1u)
#define MROWS 64             // rows per MLP block
#define HPAD 66              // padded stride for hT

// bf16 pack (RNE)
__device__ __forceinline__ unsigned short f2bf(float f) {
    unsigned u = __float_as_uint(f);
    u = u + 0x7FFFu + ((u >> 16) & 1u);
    return (unsigned short)(u >> 16);
}

// K0: convert left (f32) -> left16 (bf16), 2 elems/thread
__global__ void convert_left_kernel(const float* __restrict__ left,
                                    unsigned* __restrict__ left16, int n2) {
    int i = blockIdx.x * blockDim.x + threadIdx.x;
    if (i >= n2) return;
    float2 v = ((const float2*)left)[i];
    left16[i] = (unsigned)f2bf(v.x) | ((unsigned)f2bf(v.y) << 16);
}

// K1: bcur[b] = b*slot
__global__ void init_bcur_kernel(int* __restrict__ bcur, int nb, int slot) {
    int t = threadIdx.x;
    if (t < nb) bcur[t] = t * slot;
}

// K2: partition edges into slack-slotted buckets (LDS-staged coalesced
// writes) + total = sum(w). PROVEN 89us shape: 256 threads, 3 blocks/CU.
// LDS-op pipe is the serialized resource; more waves/CU do NOT help (r12).
__global__ __launch_bounds__(256) void partition_kernel(
    const int2* __restrict__ eidx, const float* __restrict__ w, int n_edges,
    int* __restrict__ bcursor, int2* __restrict__ bsorted,
    float* __restrict__ total) {
    __shared__ int lh[256];
    __shared__ int lo[256];
    __shared__ int go[256];
    __shared__ int lcur[256];
    __shared__ int2 stage[CHUNK];
    __shared__ int dstg[CHUNK];
    int t = threadIdx.x;
    int base = blockIdx.x * CHUNK;
    int cnt = min(CHUNK, n_edges - base);

    lh[t] = 0;
    __syncthreads();
    #pragma unroll
    for (int k = 0; k < CHUNK / 256; ++k) {
        int e = base + t + k * 256;
        if (e < n_edges) atomicAdd(&lh[eidx[e].x >> BSHIFT], 1);
    }
    __syncthreads();
    int v = lh[t];
    lo[t] = v;
    __syncthreads();
    for (int off = 1; off < 256; off <<= 1) {
        int u = (t >= off) ? lo[t - off] : 0;
        __syncthreads();
        lo[t] += u;
        __syncthreads();
    }
    int excl = lo[t] - v;
    go[t] = (v > 0) ? atomicAdd(&bcursor[t], v) : 0;
    __syncthreads();
    lo[t] = excl;
    lcur[t] = excl;
    __syncthreads();

    float s = 0.f;
    #pragma unroll
    for (int k = 0; k < CHUNK / 256; ++k) {
        int e = base + t + k * 256;
        if (e < n_edges) {
            int2 rc = eidx[e];
            float wv = w[e];
            s += wv;
            int b = rc.x >> BSHIFT;
            unsigned rl = (unsigned)(rc.x & (BROWS - 1));
            int p = atomicAdd(&lcur[b], 1);
            stage[p] = make_int2((int)((rl << COLBITS) | (unsigned)rc.y),
                                 __float_as_int(wv));
            dstg[p] = go[b] + (p - lo[b]);
        }
    }
    #pragma unroll
    for (int off = 32; off > 0; off >>= 1) s += __shfl_down(s, off, 64);
    if ((t & 63) == 0) atomicAdd(total, s);
    __syncthreads();
    #pragma unroll
    for (int k = 0; k < CHUNK / 256; ++k) {
        int s2 = t + k * 256;
        if (s2 < cnt) bsorted[dstg[s2]] = stage[s2];
    }
}

// K3: dense bases: sbase[b] = exclusive scan of (bcur[b] - b*slot)
__global__ __launch_bounds__(256, 1) void count_scan_kernel(
    const int* __restrict__ bcur, int* __restrict__ sbase, int nb, int slot) {
    __shared__ int ssc[256];
    int t = threadIdx.x;
    int cnt = (t < nb) ? (bcur[t] - t * slot) : 0;
    ssc[t] = cnt;
    __syncthreads();
    for (int off = 1; off < 256; off <<= 1) {
        int u = (t >= off) ? ssc[t - off] : 0;
        __syncthreads();
        ssc[t] += u;
        __syncthreads();
    }
    if (t < nb) sbase[t] = ssc[t] - cnt;
}

// K4: one block (1024 thr, 16 waves) per bucket: per-row offsets in LDS +
// L2-local row scatter into DENSE sorted2; writes dense offs[row] starts.
// Only 196 blocks -> 16 waves/block quarters the serial chain per bucket.
__global__ __launch_bounds__(1024) void local_rowsort_kernel(
    const int2* __restrict__ bsorted, const int* __restrict__ bcur,
    const int* __restrict__ sbase, int* __restrict__ offs,
    int2* __restrict__ sorted2, int n_right, int slot) {
    __shared__ int lhist[BROWS];
    __shared__ int lcur[BROWS];
    __shared__ int ps[BROWS];
    int b = blockIdx.x;
    int t = threadIdx.x;
    int src0 = b * slot;
    int send = min(bcur[b], src0 + slot);
    int dbase = sbase[b];
    int row0 = b << BSHIFT;
    int nrows = min(BROWS, n_right - row0);

    if (t < BROWS) lhist[t] = 0;
    __syncthreads();
    for (int e = src0 + t; e < send; e += 1024)
        atomicAdd(&lhist[((unsigned)bsorted[e].x) >> COLBITS], 1);
    __syncthreads();

    if (t < BROWS) ps[t] = lhist[t];
    __syncthreads();
    for (int off = 1; off < BROWS; off <<= 1) {
        int u = (t < BROWS && t >= off) ? ps[t - off] : 0;
        __syncthreads();
        if (t < BROWS) ps[t] += u;
        __syncthreads();
    }
    if (t < BROWS) {
        int excl = ps[t] - lhist[t];
        lcur[t] = excl;
        if (t < nrows) offs[row0 + t] = dbase + excl;
    }
    __syncthreads();

    int e = src0 + t;
    for (; e + 3 * 1024 < send; e += 4 * 1024) {
        int2 e0 = bsorted[e + 0 * 1024];
        int2 e1 = bsorted[e + 1 * 1024];
        int2 e2 = bsorted[e + 2 * 1024];
        int2 e3 = bsorted[e + 3 * 1024];
        int p0 = atomicAdd(&lcur[((unsigned)e0.x) >> COLBITS], 1);
        int p1 = atomicAdd(&lcur[((unsigned)e1.x) >> COLBITS], 1);
        int p2 = atomicAdd(&lcur[((unsigned)e2.x) >> COLBITS], 1);
        int p3 = atomicAdd(&lcur[((unsigned)e3.x) >> COLBITS], 1);
        sorted2[dbase + p0] = e0;
        sorted2[dbase + p1] = e1;
        sorted2[dbase + p2] = e2;
        sorted2[dbase + p3] = e3;
    }
    for (; e < send; e += 1024) {
        int2 e0 = bsorted[e];
        int p0 = atomicAdd(&lcur[((unsigned)e0.x) >> COLBITS], 1);
        sorted2[dbase + p0] = e0;
    }
}

// K5: one wave per row, 16 edges per iteration (2 independent octet chains).
// lane = (sub<<3)|d8. Two payload loads + two table gathers in flight.
__global__ void seg_gather_bf16_kernel(const int2* __restrict__ sorted,
                                       const int* __restrict__ offs,
                                       const uint4* __restrict__ left16o,
                                       const float* __restrict__ right,
                                       const float* __restrict__ c,
                                       const float* __restrict__ temp,
                                       const float* __restrict__ total,
                                       float* __restrict__ hout, int n_right,
                                       int n_edges, int offs_are_ends) {
    int gid = blockIdx.x * blockDim.x + threadIdx.x;
    int wid = gid >> 6;
    int lane = gid & 63;
    if (wid >= n_right) return;
    int start, end;
    if (offs_are_ends) {
        end = offs[wid];
        start = (wid == 0) ? 0 : offs[wid - 1];
    } else {
        start = offs[wid];
        end = (wid + 1 < n_right) ? offs[wid + 1] : n_edges;
    }

    int sub = lane >> 3;       // edge within octet
    int d8  = lane & 7;        // dim octet

    float cv = c[wid];
    float inv = 1.0f / fmaxf(total[0], 1.0f);
    float t1 = temp[1];

    float a0 = 0.f, a1 = 0.f, a2 = 0.f, a3 = 0.f;
    float a4 = 0.f, a5 = 0.f, a6 = 0.f, a7 = 0.f;

    if (start < end) {
        int last = end - 1;
        int i0 = start + sub;
        int2 s0 = sorted[min(i0, last)];
        int2 s1 = sorted[min(i0 + 8, last)];
        for (int base = start; base < end; base += 16) {
            int2 c0 = s0;
            int2 c1 = s1;
            int nb0 = base + 16;
            if (nb0 < end) {
                s0 = sorted[min(nb0 + sub, last)];
                s1 = sorted[min(nb0 + 8 + sub, last)];
            }
            float w0 = (base + sub < end) ? __int_as_float(c0.y) : 0.f;
            float w1 = (base + 8 + sub < end) ? __int_as_float(c1.y) : 0.f;
            unsigned col0 = (unsigned)c0.x & COLMASK;
            unsigned col1 = (unsigned)c1.x & COLMASK;
            uint4 p0 = left16o[(size_t)col0 * 8 + d8];
            uint4 p1 = left16o[(size_t)col1 * 8 + d8];
            a0 = fmaf(w0, __uint_as_float(p0.x << 16), a0);
            a1 = fmaf(w0, __uint_as_float(p0.x & 0xffff0000u), a1);
            a2 = fmaf(w0, __uint_as_float(p0.y << 16), a2);
            a3 = fmaf(w0, __uint_as_float(p0.y & 0xffff0000u), a3);
            a4 = fmaf(w0, __uint_as_float(p0.z << 16), a4);
            a5 = fmaf(w0, __uint_as_float(p0.z & 0xffff0000u), a5);
            a6 = fmaf(w0, __uint_as_float(p0.w << 16), a6);
            a7 = fmaf(w0, __uint_as_float(p0.w & 0xffff0000u), a7);
            a0 = fmaf(w1, __uint_as_float(p1.x << 16), a0);
            a1 = fmaf(w1, __uint_as_float(p1.x & 0xffff0000u), a1);
            a2 = fmaf(w1, __uint_as_float(p1.y << 16), a2);
            a3 = fmaf(w1, __uint_as_float(p1.y & 0xffff0000u), a3);
            a4 = fmaf(w1, __uint_as_float(p1.z << 16), a4);
            a5 = fmaf(w1, __uint_as_float(p1.z & 0xffff0000u), a5);
            a6 = fmaf(w1, __uint_as_float(p1.w << 16), a6);
            a7 = fmaf(w1, __uint_as_float(p1.w & 0xffff0000u), a7);
        }
    }

    #define RED8(x) x += __shfl_xor(x, 8, 64); x += __shfl_xor(x, 16, 64); \
                    x += __shfl_xor(x, 32, 64);
    RED8(a0) RED8(a1) RED8(a2) RED8(a3) RED8(a4) RED8(a5) RED8(a6) RED8(a7)
    #undef RED8

    if (lane < 8) {
        const float4* rp = (const float4*)(right + (size_t)wid * EMB);
        float4 r0 = rp[2 * lane];
        float4 r1 = rp[2 * lane + 1];
        float4 h0, h1;
        h0.x = r0.x + t1 * (cv - a0 * inv);
        h0.y = r0.y + t1 * (cv - a1 * inv);
        h0.z = r0.z + t1 * (cv - a2 * inv);
        h0.w = r0.w + t1 * (cv - a3 * inv);
        h1.x = r1.x + t1 * (cv - a4 * inv);
        h1.y = r1.y + t1 * (cv - a5 * inv);
        h1.z = r1.z + t1 * (cv - a6 * inv);
        h1.w = r1.w + t1 * (cv - a7 * inv);
        float4* op = (float4*)(hout + (size_t)wid * EMB);
        op[2 * lane] = h0;
        op[2 * lane + 1] = h1;
    }
}

// K6: tiled MLP (proven round 9).
__global__ __launch_bounds__(256, 4) void mlp_kernel(
    const float* __restrict__ W1, const float* __restrict__ b1,
    const float* __restrict__ W2, const float* __restrict__ b2,
    float* __restrict__ io, int n) {
    __shared__ float hT[64 * HPAD];
    __shared__ float h1T[64 * 64];
    int t = threadIdx.x;
    int r = t & 63;
    int q = __builtin_amdgcn_readfirstlane(t >> 6);
    int row0 = blockIdx.x * MROWS;

    #pragma unroll
    for (int i = 0; i < 16; ++i) {
        int rr = i * 4 + q;
        int gr = row0 + rr;
        float v = (gr < n) ? io[(size_t)gr * EMB + r] : 0.f;
        hT[r * HPAD + rr] = v;
    }
    __syncthreads();

    float acc[16];
    #pragma unroll
    for (int jj = 0; jj < 16; ++jj) acc[jj] = b1[q * 16 + jj];
    for (int k = 0; k < 64; ++k) {
        float hk = hT[k * HPAD + r];
        #pragma unroll
        for (int jj = 0; jj < 16; ++jj)
            acc[jj] = fmaf(hk, W1[(q * 16 + jj) * EMB + k], acc[jj]);
    }
    #pragma unroll
    for (int jj = 0; jj < 16; ++jj)
        h1T[(q * 16 + jj) * 64 + r] = fmaxf(acc[jj], 0.f);
    __syncthreads();

    #pragma unroll
    for (int jj = 0; jj < 16; ++jj) acc[jj] = b2[q * 16 + jj];
    for (int k = 0; k < 64; ++k) {
        float hk = h1T[k * 64 + r];
        #pragma unroll
        for (int jj = 0; jj < 16; ++jj)
            acc[jj] = fmaf(hk, W2[(q * 16 + jj) * EMB + k], acc[jj]);
    }
    __syncthreads();
    #pragma unroll
    for (int jj = 0; jj < 16; ++jj)
        hT[(q * 16 + jj) * HPAD + r] = acc[jj];
    __syncthreads();

    #pragma unroll
    for (int i = 0; i < 16; ++i) {
        int rr = i * 4 + q;
        int gr = row0 + rr;
        if (gr < n) io[(size_t)gr * EMB + r] = hT[r * HPAD + rr];
    }
}

// ===================== mid-path kernels (row-level hist + scans) ==========

__global__ void hist_total_kernel(const int2* __restrict__ eidx,
                                  const float* __restrict__ w, int n_edges,
                                  int* __restrict__ counts,
                                  float* __restrict__ total) {
    int gid = blockIdx.x * blockDim.x + threadIdx.x;
    int stride = gridDim.x * blockDim.x;
    float s = 0.f;
    for (int e = gid; e < n_edges; e += stride) {
        s += w[e];
        atomicAdd(&counts[eidx[e].x], 1);
    }
    #pragma unroll
    for (int off = 32; off > 0; off >>= 1) s += __shfl_down(s, off, 64);
    if ((threadIdx.x & 63) == 0) atomicAdd(total, s);
}

__global__ __launch_bounds__(1024, 1) void scan1_kernel(
    const int* __restrict__ cnt, int* __restrict__ incl,
    int* __restrict__ bsums, int n) {
    __shared__ int s[1024];
    int t = threadIdx.x;
    int i = blockIdx.x * 1024 + t;
    int v = (i < n) ? cnt[i] : 0;
    s[t] = v;
    __syncthreads();
    for (int off = 1; off < 1024; off <<= 1) {
        int u = (t >= off) ? s[t - off] : 0;
        __syncthreads();
        s[t] += u;
        __syncthreads();
    }
    if (i < n) incl[i] = s[t];
    if (t == 1023) bsums[blockIdx.x] = s[t];
}

__global__ __launch_bounds__(256, 1) void scan2_kernel(int* __restrict__ bsums, int nb) {
    __shared__ int s[256];
    int t = threadIdx.x;
    int v = (t < nb) ? bsums[t] : 0;
    s[t] = v;
    __syncthreads();
    for (int off = 1; off < 256; off <<= 1) {
        int u = (t >= off) ? s[t - off] : 0;
        __syncthreads();
        s[t] += u;
        __syncthreads();
    }
    if (t < nb) bsums[t] = s[t] - v;
}

__global__ void scan3_kernel(const int* __restrict__ incl,
                             const int* __restrict__ base,
                             int* __restrict__ offs, int n) {
    int i = blockIdx.x * blockDim.x + threadIdx.x;
    if (i >= n) return;
    offs[i] = (i == 0) ? 0 : incl[i - 1] + base[(i - 1) >> 10];
}

__global__ void scatter_kernel(const int2* __restrict__ eidx,
                               const float* __restrict__ w, int n_edges,
                               int* __restrict__ offs,
                               int2* __restrict__ sorted) {
    int gid = blockIdx.x * blockDim.x + threadIdx.x;
    int stride = gridDim.x * blockDim.x;
    for (int e = gid; e < n_edges; e += stride) {
        int2 rc = eidx[e];
        float v = w[e];
        int pos = atomicAdd(&offs[rc.x], 1);
        sorted[pos] = make_int2(rc.y, __float_as_int(v));
    }
}

// ===================== fallback (atomic path) =====================

__global__ void sum_weights_kernel(const float* __restrict__ w, int n,
                                   float* __restrict__ total) {
    int gid = blockIdx.x * blockDim.x + threadIdx.x;
    int stride = gridDim.x * blockDim.x;
    float s = 0.f;
    for (int i = gid; i < n; i += stride) s += w[i];
    #pragma unroll
    for (int off = 32; off > 0; off >>= 1) s += __shfl_down(s, off, 64);
    if ((threadIdx.x & 63) == 0) atomicAdd(total, s);
}

__global__ void edge_scatter_kernel(const int* __restrict__ idx,
                                    const float* __restrict__ w,
                                    const float* __restrict__ left,
                                    const float* __restrict__ total,
                                    float* __restrict__ conv,
                                    long long n_threads) {
    long long gid = (long long)blockIdx.x * blockDim.x + threadIdx.x;
    if (gid >= n_threads) return;
    int e = (int)(gid >> 6);
    int d = (int)(gid & 63);
    float inv = 1.0f / fmaxf(total[0], 1.0f);
    int row = idx[2 * e];
    int col = idx[2 * e + 1];
    float v = w[e] * inv;
    float msg = left[(size_t)col * EMB + d] * v;
    atomicAdd(&conv[(size_t)row * EMB + d], msg);
}

__global__ __launch_bounds__(256, 1) void fused_mlp_kernel(
    const float* __restrict__ right, const float* __restrict__ c,
    const float* __restrict__ temp,
    const float* __restrict__ W1, const float* __restrict__ b1,
    const float* __restrict__ W2, const float* __restrict__ b2,
    float* __restrict__ io, int n) {
    int r = blockIdx.x * blockDim.x + threadIdx.x;
    if (r >= n) return;
    float t1 = temp[1];
    float cv = c[r];
    float h[EMB];
    const float4* rp = (const float4*)(right + (size_t)r * EMB);
    const float4* qp = (const float4*)(io + (size_t)r * EMB);
    #pragma unroll
    for (int qq = 0; qq < EMB / 4; ++qq) {
        float4 rv = rp[qq];
        float4 qv = qp[qq];
        h[4 * qq + 0] = rv.x + t1 * (cv - qv.x);
        h[4 * qq + 1] = rv.y + t1 * (cv - qv.y);
        h[4 * qq + 2] = rv.z + t1 * (cv - qv.z);
        h[4 * qq + 3] = rv.w + t1 * (cv - qv.w);
    }
    float h1[EMB];
    #pragma unroll
    for (int j = 0; j < EMB; j += 4) {
        float s0 = b1[j], s1 = b1[j + 1], s2 = b1[j + 2], s3 = b1[j + 3];
        #pragma unroll
        for (int k = 0; k < EMB; ++k) {
            float hk = h[k];
            s0 = fmaf(hk, W1[(j + 0) * EMB + k], s0);
            s1 = fmaf(hk, W1[(j + 1) * EMB + k], s1);
            s2 = fmaf(hk, W1[(j + 2) * EMB + k], s2);
            s3 = fmaf(hk, W1[(j + 3) * EMB + k], s3);
        }
        h1[j] = fmaxf(s0, 0.f);
        h1[j + 1] = fmaxf(s1, 0.f);
        h1[j + 2] = fmaxf(s2, 0.f);
        h1[j + 3] = fmaxf(s3, 0.f);
    }
    float4* op = (float4*)(io + (size_t)r * EMB);
    #pragma unroll
    for (int j = 0; j < EMB; j += 4) {
        float s0 = b2[j], s1 = b2[j + 1], s2 = b2[j + 2], s3 = b2[j + 3];
        #pragma unroll
        for (int k = 0; k < EMB; ++k) {
            float hk = h1[k];
            s0 = fmaf(hk, W2[(j + 0) * EMB + k], s0);
            s1 = fmaf(hk, W2[(j + 1) * EMB + k], s1);
            s2 = fmaf(hk, W2[(j + 2) * EMB + k], s2);
            s3 = fmaf(hk, W2[(j + 3) * EMB + k], s3);
        }
        op[j / 4] = make_float4(s0, s1, s2, s3);
    }
}

// ===================== launch =====================

extern "C" void kernel_launch(void* const* d_in, const int* in_sizes, int n_in,
                              void* d_out, int out_size, void* d_ws, size_t ws_size,
                              hipStream_t stream) {
    const float* left   = (const float*)d_in[0];
    const int*   eidx   = (const int*)d_in[2];
    const float* ew     = (const float*)d_in[3];
    const float* right  = (const float*)d_in[4];
    const float* c      = (const float*)d_in[5];
    const float* temp   = (const float*)d_in[7];
    const float* W1     = (const float*)d_in[8];
    const float* b1     = (const float*)d_in[9];
    const float* W2     = (const float*)d_in[10];
    const float* b2     = (const float*)d_in[11];

    const int n_edges = in_sizes[3];
    const int n_right = in_sizes[4] / EMB;
    const int n_left  = in_sizes[0] / EMB;
    float* out = (float*)d_out;

    const int nb = (n_right + BROWS - 1) >> BSHIFT;
    const int nblocks_scan = (n_right + 1023) / 1024;

    auto align256 = [](size_t x) { return (x + 255) & ~(size_t)255; };

    int slot = n_edges / (nb > 0 ? nb : 1);
    slot += slot / 16 + 128;

    size_t off_bcur    = 64;
    size_t off_sbase   = align256(off_bcur + (size_t)nb * 4);
    size_t off_offs    = align256(off_sbase + (size_t)(nb + 1) * 4);
    size_t off_bsorted = align256(off_offs + (size_t)n_right * 4);
    size_t off_sorted2 = align256(off_bsorted + ((size_t)nb * slot + slot) * 8);
    size_t off_left16f = align256(off_sorted2 + (size_t)n_edges * 8);
    size_t req_full    = off_left16f + (size_t)n_left * EMB * 2;

    size_t m_off_offs   = 64;
    size_t m_off_incl   = align256(m_off_offs + (size_t)n_right * 4);
    size_t m_off_bsum   = align256(m_off_incl + (size_t)n_right * 4);
    size_t m_off_sorted = align256(m_off_bsum + 1024);
    size_t m_off_left16 = align256(m_off_sorted + (size_t)n_edges * 8);
    size_t req_mid      = m_off_left16 + (size_t)n_left * EMB * 2;

    bool common_ok = (nb <= 256) && (nblocks_scan <= 256) &&
                     (n_left <= (1 << COLBITS)) && (BROWS * nb >= n_right);

    if (common_ok && ws_size >= req_full) {
        // ---------- full path ----------
        char* ws = (char*)d_ws;
        float* total = (float*)ws;
        int* bcur = (int*)(ws + off_bcur);
        int* sbase = (int*)(ws + off_sbase);
        int* offs = (int*)(ws + off_offs);
        int2* bsorted = (int2*)(ws + off_bsorted);
        int2* sorted2 = (int2*)(ws + off_sorted2);
        unsigned short* left16 = (unsigned short*)(ws + off_left16f);

        hipMemsetAsync(ws, 0, 64, stream);  // total

        int n2 = n_left * EMB / 2;
        convert_left_kernel<<<(n2 + 255) / 256, 256, 0, stream>>>(
            left, (unsigned*)left16, n2);
        init_bcur_kernel<<<1, 256, 0, stream>>>(bcur, nb, slot);
        {
            int nchunks = (n_edges + CHUNK - 1) / CHUNK;
            partition_kernel<<<nchunks, 256, 0, stream>>>(
                (const int2*)eidx, ew, n_edges, bcur, bsorted, total);
        }
        count_scan_kernel<<<1, 256, 0, stream>>>(bcur, sbase, nb, slot);
        local_rowsort_kernel<<<nb, 1024, 0, stream>>>(bsorted, bcur, sbase, offs,
                                                      sorted2, n_right, slot);
        {
            long long n_threads = (long long)n_right * EMB;
            int blocks = (int)((n_threads + 255) / 256);
            seg_gather_bf16_kernel<<<blocks, 256, 0, stream>>>(
                sorted2, offs, (const uint4*)left16, right, c, temp, total,
                out, n_right, n_edges, 0);
        }
        mlp_kernel<<<(n_right + MROWS - 1) / MROWS, 256, 0, stream>>>(
            W1, b1, W2, b2, out, n_right);
    } else if (common_ok && ws_size >= req_mid) {
        // ---------- mid path ----------
        char* ws = (char*)d_ws;
        float* total = (float*)ws;
        int* offs = (int*)(ws + m_off_offs);
        int* incl = (int*)(ws + m_off_incl);
        int* bsum = (int*)(ws + m_off_bsum);
        int2* sorted = (int2*)(ws + m_off_sorted);
        unsigned short* left16 = (unsigned short*)(ws + m_off_left16);

        hipMemsetAsync(ws, 0, m_off_offs + (size_t)n_right * 4, stream);

        int n2 = n_left * EMB / 2;
        convert_left_kernel<<<(n2 + 255) / 256, 256, 0, stream>>>(
            left, (unsigned*)left16, n2);
        hist_total_kernel<<<2048, 256, 0, stream>>>((const int2*)eidx, ew,
                                                    n_edges, offs, total);
        scan1_kernel<<<nblocks_scan, 1024, 0, stream>>>(offs, incl, bsum, n_right);
        scan2_kernel<<<1, 256, 0, stream>>>(bsum, nblocks_scan);
        scan3_kernel<<<(n_right + 255) / 256, 256, 0, stream>>>(incl, bsum, offs,
                                                                n_right);
        scatter_kernel<<<2048, 256, 0, stream>>>((const int2*)eidx, ew, n_edges,
                                                 offs, sorted);
        {
            long long n_threads = (long long)n_right * EMB;
            int blocks = (int)((n_threads + 255) / 256);
            seg_gather_bf16_kernel<<<blocks, 256, 0, stream>>>(
                sorted, offs, (const uint4*)left16, right, c, temp, total,
                out, n_right, n_edges, 1);
        }
        mlp_kernel<<<(n_right + MROWS - 1) / MROWS, 256, 0, stream>>>(
            W1, b1, W2, b2, out, n_right);
    } else {
        // ---------- fallback: atomic path ----------
        float* total = (float*)d_ws;
        hipMemsetAsync(d_out, 0, (size_t)out_size * sizeof(float), stream);
        hipMemsetAsync(d_ws, 0, sizeof(float), stream);
        sum_weights_kernel<<<2048, 256, 0, stream>>>(ew, n_edges, total);
        long long n_threads = (long long)n_edges * EMB;
        long long blocks = (n_threads + 255) / 256;
        edge_scatter_kernel<<<(int)blocks, 256, 0, stream>>>(
            eidx, ew, left, total, out, n_threads);
        int mblocks = (n_right + 255) / 256;
        fused_mlp_kernel<<<mblocks, 256, 0, stream>>>(right, c, temp, W1, b1, W2,
                                                      b2, out, n_right);
    }
}

// Round 14
// 227.139 us; speedup vs baseline: 6.6129x; 1.0138x over previous
//
#include <hip/hip_runtime.h>

#define EMB 64
#define BROWS 512            // rows per bucket
#define BSHIFT 9             // log2(BROWS)
#define CHUNK 4096           // edges per partition block
#define COLBITS 23
#define COLMASK ((1u << COLBITS) - 1u)
#define MROWS 64             // rows per MLP block
#define HPAD 66              // padded stride for hT

// bf16 pack (RNE)
__device__ __forceinline__ unsigned short f2bf(float f) {
    unsigned u = __float_as_uint(f);
    u = u + 0x7FFFu + ((u >> 16) & 1u);
    return (unsigned short)(u >> 16);
}

// K0: convert left (f32) -> left16 (bf16), 2 elems/thread
__global__ void convert_left_kernel(const float* __restrict__ left,
                                    unsigned* __restrict__ left16, int n2) {
    int i = blockIdx.x * blockDim.x + threadIdx.x;
    if (i >= n2) return;
    float2 v = ((const float2*)left)[i];
    left16[i] = (unsigned)f2bf(v.x) | ((unsigned)f2bf(v.y) << 16);
}

// K1: bcur[b] = b*slot
__global__ void init_bcur_kernel(int* __restrict__ bcur, int nb, int slot) {
    int t = threadIdx.x;
    if (t < nb) bcur[t] = t * slot;
}

// K2: single-pass partition (register-stash). Per edge: ONE LDS atomic
// (rank), edges kept in regs; counts scanned once; LDS-staged coalesced
// flush kept (r10 showed direct global scatter is transaction-bound).
// Halves partition's atomic wave-ops vs the two-pass version.
__global__ __launch_bounds__(256) void partition_kernel(
    const int2* __restrict__ eidx, const float* __restrict__ w, int n_edges,
    int* __restrict__ bcursor, int2* __restrict__ bsorted,
    float* __restrict__ total) {
    __shared__ int lcur[256];
    __shared__ int lo[256];
    __shared__ int go[256];
    __shared__ int ps[256];
    __shared__ int2 stage[CHUNK];
    __shared__ int dstg[CHUNK];
    int t = threadIdx.x;
    int base = blockIdx.x * CHUNK;
    int cnt = min(CHUNK, n_edges - base);

    lcur[t] = 0;
    __syncthreads();

    // phase A: read edges into regs, rank via single LDS atomic
    int2 pay[CHUNK / 256];
    int meta[CHUNK / 256];      // (bucket<<16) | rank, or -1
    float s = 0.f;
    #pragma unroll
    for (int k = 0; k < CHUNK / 256; ++k) {
        int e = base + t + k * 256;
        if (e < n_edges) {
            int2 rc = eidx[e];
            float wv = w[e];
            s += wv;
            int b = rc.x >> BSHIFT;
            unsigned rl = (unsigned)(rc.x & (BROWS - 1));
            pay[k] = make_int2((int)((rl << COLBITS) | (unsigned)rc.y),
                               __float_as_int(wv));
            int rank = atomicAdd(&lcur[b], 1);
            meta[k] = (b << 16) | rank;
        } else {
            meta[k] = -1;
        }
    }
    #pragma unroll
    for (int off = 32; off > 0; off >>= 1) s += __shfl_down(s, off, 64);
    if ((t & 63) == 0) atomicAdd(total, s);
    __syncthreads();

    // phase B: scan counts -> local excl offsets; reserve global runs
    int v = lcur[t];
    ps[t] = v;
    __syncthreads();
    for (int off = 1; off < 256; off <<= 1) {
        int u = (t >= off) ? ps[t - off] : 0;
        __syncthreads();
        ps[t] += u;
        __syncthreads();
    }
    lo[t] = ps[t] - v;                       // exclusive local offset
    go[t] = (v > 0) ? atomicAdd(&bcursor[t], v) : 0;
    __syncthreads();

    // phase C: place payloads into stage (bucket-grouped) + dest indices
    #pragma unroll
    for (int k = 0; k < CHUNK / 256; ++k) {
        int m = meta[k];
        if (m >= 0) {
            int b = m >> 16;
            int rank = m & 0xffff;
            int p = lo[b] + rank;
            stage[p] = pay[k];
            dstg[p] = go[b] + rank;
        }
    }
    __syncthreads();

    // flush: coalesced reads, bucket-run-contiguous global writes
    #pragma unroll
    for (int k = 0; k < CHUNK / 256; ++k) {
        int s2 = t + k * 256;
        if (s2 < cnt) bsorted[dstg[s2]] = stage[s2];
    }
}

// K3: dense bases: sbase[b] = exclusive scan of (bcur[b] - b*slot)
__global__ __launch_bounds__(256, 1) void count_scan_kernel(
    const int* __restrict__ bcur, int* __restrict__ sbase, int nb, int slot) {
    __shared__ int ssc[256];
    int t = threadIdx.x;
    int cnt = (t < nb) ? (bcur[t] - t * slot) : 0;
    ssc[t] = cnt;
    __syncthreads();
    for (int off = 1; off < 256; off <<= 1) {
        int u = (t >= off) ? ssc[t - off] : 0;
        __syncthreads();
        ssc[t] += u;
        __syncthreads();
    }
    if (t < nb) sbase[t] = ssc[t] - cnt;
}

// K4: one block (1024 thr, 16 waves) per bucket: per-row offsets in LDS +
// L2-local row scatter into DENSE sorted2; writes dense offs[row] starts.
__global__ __launch_bounds__(1024) void local_rowsort_kernel(
    const int2* __restrict__ bsorted, const int* __restrict__ bcur,
    const int* __restrict__ sbase, int* __restrict__ offs,
    int2* __restrict__ sorted2, int n_right, int slot) {
    __shared__ int lhist[BROWS];
    __shared__ int lcur[BROWS];
    __shared__ int ps[BROWS];
    int b = blockIdx.x;
    int t = threadIdx.x;
    int src0 = b * slot;
    int send = min(bcur[b], src0 + slot);
    int dbase = sbase[b];
    int row0 = b << BSHIFT;
    int nrows = min(BROWS, n_right - row0);

    if (t < BROWS) lhist[t] = 0;
    __syncthreads();
    for (int e = src0 + t; e < send; e += 1024)
        atomicAdd(&lhist[((unsigned)bsorted[e].x) >> COLBITS], 1);
    __syncthreads();

    if (t < BROWS) ps[t] = lhist[t];
    __syncthreads();
    for (int off = 1; off < BROWS; off <<= 1) {
        int u = (t < BROWS && t >= off) ? ps[t - off] : 0;
        __syncthreads();
        if (t < BROWS) ps[t] += u;
        __syncthreads();
    }
    if (t < BROWS) {
        int excl = ps[t] - lhist[t];
        lcur[t] = excl;
        if (t < nrows) offs[row0 + t] = dbase + excl;
    }
    __syncthreads();

    int e = src0 + t;
    for (; e + 3 * 1024 < send; e += 4 * 1024) {
        int2 e0 = bsorted[e + 0 * 1024];
        int2 e1 = bsorted[e + 1 * 1024];
        int2 e2 = bsorted[e + 2 * 1024];
        int2 e3 = bsorted[e + 3 * 1024];
        int p0 = atomicAdd(&lcur[((unsigned)e0.x) >> COLBITS], 1);
        int p1 = atomicAdd(&lcur[((unsigned)e1.x) >> COLBITS], 1);
        int p2 = atomicAdd(&lcur[((unsigned)e2.x) >> COLBITS], 1);
        int p3 = atomicAdd(&lcur[((unsigned)e3.x) >> COLBITS], 1);
        sorted2[dbase + p0] = e0;
        sorted2[dbase + p1] = e1;
        sorted2[dbase + p2] = e2;
        sorted2[dbase + p3] = e3;
    }
    for (; e < send; e += 1024) {
        int2 e0 = bsorted[e];
        int p0 = atomicAdd(&lcur[((unsigned)e0.x) >> COLBITS], 1);
        sorted2[dbase + p0] = e0;
    }
}

// K5: one wave per row, 16 edges per iteration (2 independent octet chains).
__global__ void seg_gather_bf16_kernel(const int2* __restrict__ sorted,
                                       const int* __restrict__ offs,
                                       const uint4* __restrict__ left16o,
                                       const float* __restrict__ right,
                                       const float* __restrict__ c,
                                       const float* __restrict__ temp,
                                       const float* __restrict__ total,
                                       float* __restrict__ hout, int n_right,
                                       int n_edges, int offs_are_ends) {
    int gid = blockIdx.x * blockDim.x + threadIdx.x;
    int wid = gid >> 6;
    int lane = gid & 63;
    if (wid >= n_right) return;
    int start, end;
    if (offs_are_ends) {
        end = offs[wid];
        start = (wid == 0) ? 0 : offs[wid - 1];
    } else {
        start = offs[wid];
        end = (wid + 1 < n_right) ? offs[wid + 1] : n_edges;
    }

    int sub = lane >> 3;       // edge within octet
    int d8  = lane & 7;        // dim octet

    float cv = c[wid];
    float inv = 1.0f / fmaxf(total[0], 1.0f);
    float t1 = temp[1];

    float a0 = 0.f, a1 = 0.f, a2 = 0.f, a3 = 0.f;
    float a4 = 0.f, a5 = 0.f, a6 = 0.f, a7 = 0.f;

    if (start < end) {
        int last = end - 1;
        int i0 = start + sub;
        int2 s0 = sorted[min(i0, last)];
        int2 s1 = sorted[min(i0 + 8, last)];
        for (int base = start; base < end; base += 16) {
            int2 c0 = s0;
            int2 c1 = s1;
            int nb0 = base + 16;
            if (nb0 < end) {
                s0 = sorted[min(nb0 + sub, last)];
                s1 = sorted[min(nb0 + 8 + sub, last)];
            }
            float w0 = (base + sub < end) ? __int_as_float(c0.y) : 0.f;
            float w1 = (base + 8 + sub < end) ? __int_as_float(c1.y) : 0.f;
            unsigned col0 = (unsigned)c0.x & COLMASK;
            unsigned col1 = (unsigned)c1.x & COLMASK;
            uint4 p0 = left16o[(size_t)col0 * 8 + d8];
            uint4 p1 = left16o[(size_t)col1 * 8 + d8];
            a0 = fmaf(w0, __uint_as_float(p0.x << 16), a0);
            a1 = fmaf(w0, __uint_as_float(p0.x & 0xffff0000u), a1);
            a2 = fmaf(w0, __uint_as_float(p0.y << 16), a2);
            a3 = fmaf(w0, __uint_as_float(p0.y & 0xffff0000u), a3);
            a4 = fmaf(w0, __uint_as_float(p0.z << 16), a4);
            a5 = fmaf(w0, __uint_as_float(p0.z & 0xffff0000u), a5);
            a6 = fmaf(w0, __uint_as_float(p0.w << 16), a6);
            a7 = fmaf(w0, __uint_as_float(p0.w & 0xffff0000u), a7);
            a0 = fmaf(w1, __uint_as_float(p1.x << 16), a0);
            a1 = fmaf(w1, __uint_as_float(p1.x & 0xffff0000u), a1);
            a2 = fmaf(w1, __uint_as_float(p1.y << 16), a2);
            a3 = fmaf(w1, __uint_as_float(p1.y & 0xffff0000u), a3);
            a4 = fmaf(w1, __uint_as_float(p1.z << 16), a4);
            a5 = fmaf(w1, __uint_as_float(p1.z & 0xffff0000u), a5);
            a6 = fmaf(w1, __uint_as_float(p1.w << 16), a6);
            a7 = fmaf(w1, __uint_as_float(p1.w & 0xffff0000u), a7);
        }
    }

    #define RED8(x) x += __shfl_xor(x, 8, 64); x += __shfl_xor(x, 16, 64); \
                    x += __shfl_xor(x, 32, 64);
    RED8(a0) RED8(a1) RED8(a2) RED8(a3) RED8(a4) RED8(a5) RED8(a6) RED8(a7)
    #undef RED8

    if (lane < 8) {
        const float4* rp = (const float4*)(right + (size_t)wid * EMB);
        float4 r0 = rp[2 * lane];
        float4 r1 = rp[2 * lane + 1];
        float4 h0, h1;
        h0.x = r0.x + t1 * (cv - a0 * inv);
        h0.y = r0.y + t1 * (cv - a1 * inv);
        h0.z = r0.z + t1 * (cv - a2 * inv);
        h0.w = r0.w + t1 * (cv - a3 * inv);
        h1.x = r1.x + t1 * (cv - a4 * inv);
        h1.y = r1.y + t1 * (cv - a5 * inv);
        h1.z = r1.z + t1 * (cv - a6 * inv);
        h1.w = r1.w + t1 * (cv - a7 * inv);
        float4* op = (float4*)(hout + (size_t)wid * EMB);
        op[2 * lane] = h0;
        op[2 * lane + 1] = h1;
    }
}

// K6: tiled MLP (proven round 9).
__global__ __launch_bounds__(256, 4) void mlp_kernel(
    const float* __restrict__ W1, const float* __restrict__ b1,
    const float* __restrict__ W2, const float* __restrict__ b2,
    float* __restrict__ io, int n) {
    __shared__ float hT[64 * HPAD];
    __shared__ float h1T[64 * 64];
    int t = threadIdx.x;
    int r = t & 63;
    int q = __builtin_amdgcn_readfirstlane(t >> 6);
    int row0 = blockIdx.x * MROWS;

    #pragma unroll
    for (int i = 0; i < 16; ++i) {
        int rr = i * 4 + q;
        int gr = row0 + rr;
        float v = (gr < n) ? io[(size_t)gr * EMB + r] : 0.f;
        hT[r * HPAD + rr] = v;
    }
    __syncthreads();

    float acc[16];
    #pragma unroll
    for (int jj = 0; jj < 16; ++jj) acc[jj] = b1[q * 16 + jj];
    for (int k = 0; k < 64; ++k) {
        float hk = hT[k * HPAD + r];
        #pragma unroll
        for (int jj = 0; jj < 16; ++jj)
            acc[jj] = fmaf(hk, W1[(q * 16 + jj) * EMB + k], acc[jj]);
    }
    #pragma unroll
    for (int jj = 0; jj < 16; ++jj)
        h1T[(q * 16 + jj) * 64 + r] = fmaxf(acc[jj], 0.f);
    __syncthreads();

    #pragma unroll
    for (int jj = 0; jj < 16; ++jj) acc[jj] = b2[q * 16 + jj];
    for (int k = 0; k < 64; ++k) {
        float hk = h1T[k * 64 + r];
        #pragma unroll
        for (int jj = 0; jj < 16; ++jj)
            acc[jj] = fmaf(hk, W2[(q * 16 + jj) * EMB + k], acc[jj]);
    }
    __syncthreads();
    #pragma unroll
    for (int jj = 0; jj < 16; ++jj)
        hT[(q * 16 + jj) * HPAD + r] = acc[jj];
    __syncthreads();

    #pragma unroll
    for (int i = 0; i < 16; ++i) {
        int rr = i * 4 + q;
        int gr = row0 + rr;
        if (gr < n) io[(size_t)gr * EMB + r] = hT[r * HPAD + rr];
    }
}

// ===================== mid-path kernels (row-level hist + scans) ==========

__global__ void hist_total_kernel(const int2* __restrict__ eidx,
                                  const float* __restrict__ w, int n_edges,
                                  int* __restrict__ counts,
                                  float* __restrict__ total) {
    int gid = blockIdx.x * blockDim.x + threadIdx.x;
    int stride = gridDim.x * blockDim.x;
    float s = 0.f;
    for (int e = gid; e < n_edges; e += stride) {
        s += w[e];
        atomicAdd(&counts[eidx[e].x], 1);
    }
    #pragma unroll
    for (int off = 32; off > 0; off >>= 1) s += __shfl_down(s, off, 64);
    if ((threadIdx.x & 63) == 0) atomicAdd(total, s);
}

__global__ __launch_bounds__(1024, 1) void scan1_kernel(
    const int* __restrict__ cnt, int* __restrict__ incl,
    int* __restrict__ bsums, int n) {
    __shared__ int s[1024];
    int t = threadIdx.x;
    int i = blockIdx.x * 1024 + t;
    int v = (i < n) ? cnt[i] : 0;
    s[t] = v;
    __syncthreads();
    for (int off = 1; off < 1024; off <<= 1) {
        int u = (t >= off) ? s[t - off] : 0;
        __syncthreads();
        s[t] += u;
        __syncthreads();
    }
    if (i < n) incl[i] = s[t];
    if (t == 1023) bsums[blockIdx.x] = s[t];
}

__global__ __launch_bounds__(256, 1) void scan2_kernel(int* __restrict__ bsums, int nb) {
    __shared__ int s[256];
    int t = threadIdx.x;
    int v = (t < nb) ? bsums[t] : 0;
    s[t] = v;
    __syncthreads();
    for (int off = 1; off < 256; off <<= 1) {
        int u = (t >= off) ? s[t - off] : 0;
        __syncthreads();
        s[t] += u;
        __syncthreads();
    }
    if (t < nb) bsums[t] = s[t] - v;
}

__global__ void scan3_kernel(const int* __restrict__ incl,
                             const int* __restrict__ base,
                             int* __restrict__ offs, int n) {
    int i = blockIdx.x * blockDim.x + threadIdx.x;
    if (i >= n) return;
    offs[i] = (i == 0) ? 0 : incl[i - 1] + base[(i - 1) >> 10];
}

__global__ void scatter_kernel(const int2* __restrict__ eidx,
                               const float* __restrict__ w, int n_edges,
                               int* __restrict__ offs,
                               int2* __restrict__ sorted) {
    int gid = blockIdx.x * blockDim.x + threadIdx.x;
    int stride = gridDim.x * blockDim.x;
    for (int e = gid; e < n_edges; e += stride) {
        int2 rc = eidx[e];
        float v = w[e];
        int pos = atomicAdd(&offs[rc.x], 1);
        sorted[pos] = make_int2(rc.y, __float_as_int(v));
    }
}

// ===================== fallback (atomic path) =====================

__global__ void sum_weights_kernel(const float* __restrict__ w, int n,
                                   float* __restrict__ total) {
    int gid = blockIdx.x * blockDim.x + threadIdx.x;
    int stride = gridDim.x * blockDim.x;
    float s = 0.f;
    for (int i = gid; i < n; i += stride) s += w[i];
    #pragma unroll
    for (int off = 32; off > 0; off >>= 1) s += __shfl_down(s, off, 64);
    if ((threadIdx.x & 63) == 0) atomicAdd(total, s);
}

__global__ void edge_scatter_kernel(const int* __restrict__ idx,
                                    const float* __restrict__ w,
                                    const float* __restrict__ left,
                                    const float* __restrict__ total,
                                    float* __restrict__ conv,
                                    long long n_threads) {
    long long gid = (long long)blockIdx.x * blockDim.x + threadIdx.x;
    if (gid >= n_threads) return;
    int e = (int)(gid >> 6);
    int d = (int)(gid & 63);
    float inv = 1.0f / fmaxf(total[0], 1.0f);
    int row = idx[2 * e];
    int col = idx[2 * e + 1];
    float v = w[e] * inv;
    float msg = left[(size_t)col * EMB + d] * v;
    atomicAdd(&conv[(size_t)row * EMB + d], msg);
}

__global__ __launch_bounds__(256, 1) void fused_mlp_kernel(
    const float* __restrict__ right, const float* __restrict__ c,
    const float* __restrict__ temp,
    const float* __restrict__ W1, const float* __restrict__ b1,
    const float* __restrict__ W2, const float* __restrict__ b2,
    float* __restrict__ io, int n) {
    int r = blockIdx.x * blockDim.x + threadIdx.x;
    if (r >= n) return;
    float t1 = temp[1];
    float cv = c[r];
    float h[EMB];
    const float4* rp = (const float4*)(right + (size_t)r * EMB);
    const float4* qp = (const float4*)(io + (size_t)r * EMB);
    #pragma unroll
    for (int qq = 0; qq < EMB / 4; ++qq) {
        float4 rv = rp[qq];
        float4 qv = qp[qq];
        h[4 * qq + 0] = rv.x + t1 * (cv - qv.x);
        h[4 * qq + 1] = rv.y + t1 * (cv - qv.y);
        h[4 * qq + 2] = rv.z + t1 * (cv - qv.z);
        h[4 * qq + 3] = rv.w + t1 * (cv - qv.w);
    }
    float h1[EMB];
    #pragma unroll
    for (int j = 0; j < EMB; j += 4) {
        float s0 = b1[j], s1 = b1[j + 1], s2 = b1[j + 2], s3 = b1[j + 3];
        #pragma unroll
        for (int k = 0; k < EMB; ++k) {
            float hk = h[k];
            s0 = fmaf(hk, W1[(j + 0) * EMB + k], s0);
            s1 = fmaf(hk, W1[(j + 1) * EMB + k], s1);
            s2 = fmaf(hk, W1[(j + 2) * EMB + k], s2);
            s3 = fmaf(hk, W1[(j + 3) * EMB + k], s3);
        }
        h1[j] = fmaxf(s0, 0.f);
        h1[j + 1] = fmaxf(s1, 0.f);
        h1[j + 2] = fmaxf(s2, 0.f);
        h1[j + 3] = fmaxf(s3, 0.f);
    }
    float4* op = (float4*)(io + (size_t)r * EMB);
    #pragma unroll
    for (int j = 0; j < EMB; j += 4) {
        float s0 = b2[j], s1 = b2[j + 1], s2 = b2[j + 2], s3 = b2[j + 3];
        #pragma unroll
        for (int k = 0; k < EMB; ++k) {
            float hk = h1[k];
            s0 = fmaf(hk, W2[(j + 0) * EMB + k], s0);
            s1 = fmaf(hk, W2[(j + 1) * EMB + k], s1);
            s2 = fmaf(hk, W2[(j + 2) * EMB + k], s2);
            s3 = fmaf(hk, W2[(j + 3) * EMB + k], s3);
        }
        op[j / 4] = make_float4(s0, s1, s2, s3);
    }
}

// ===================== launch =====================

extern "C" void kernel_launch(void* const* d_in, const int* in_sizes, int n_in,
                              void* d_out, int out_size, void* d_ws, size_t ws_size,
                              hipStream_t stream) {
    const float* left   = (const float*)d_in[0];
    const int*   eidx   = (const int*)d_in[2];
    const float* ew     = (const float*)d_in[3];
    const float* right  = (const float*)d_in[4];
    const float* c      = (const float*)d_in[5];
    const float* temp   = (const float*)d_in[7];
    const float* W1     = (const float*)d_in[8];
    const float* b1     = (const float*)d_in[9];
    const float* W2     = (const float*)d_in[10];
    const float* b2     = (const float*)d_in[11];

    const int n_edges = in_sizes[3];
    const int n_right = in_sizes[4] / EMB;
    const int n_left  = in_sizes[0] / EMB;
    float* out = (float*)d_out;

    const int nb = (n_right + BROWS - 1) >> BSHIFT;
    const int nblocks_scan = (n_right + 1023) / 1024;

    auto align256 = [](size_t x) { return (x + 255) & ~(size_t)255; };

    int slot = n_edges / (nb > 0 ? nb : 1);
    slot += slot / 16 + 128;

    size_t off_bcur    = 64;
    size_t off_sbase   = align256(off_bcur + (size_t)nb * 4);
    size_t off_offs    = align256(off_sbase + (size_t)(nb + 1) * 4);
    size_t off_bsorted = align256(off_offs + (size_t)n_right * 4);
    size_t off_sorted2 = align256(off_bsorted + ((size_t)nb * slot + slot) * 8);
    size_t off_left16f = align256(off_sorted2 + (size_t)n_edges * 8);
    size_t req_full    = off_left16f + (size_t)n_left * EMB * 2;

    size_t m_off_offs   = 64;
    size_t m_off_incl   = align256(m_off_offs + (size_t)n_right * 4);
    size_t m_off_bsum   = align256(m_off_incl + (size_t)n_right * 4);
    size_t m_off_sorted = align256(m_off_bsum + 1024);
    size_t m_off_left16 = align256(m_off_sorted + (size_t)n_edges * 8);
    size_t req_mid      = m_off_left16 + (size_t)n_left * EMB * 2;

    bool common_ok = (nb <= 256) && (nblocks_scan <= 256) &&
                     (n_left <= (1 << COLBITS)) && (BROWS * nb >= n_right) &&
                     (CHUNK <= 65536);

    if (common_ok && ws_size >= req_full) {
        // ---------- full path ----------
        char* ws = (char*)d_ws;
        float* total = (float*)ws;
        int* bcur = (int*)(ws + off_bcur);
        int* sbase = (int*)(ws + off_sbase);
        int* offs = (int*)(ws + off_offs);
        int2* bsorted = (int2*)(ws + off_bsorted);
        int2* sorted2 = (int2*)(ws + off_sorted2);
        unsigned short* left16 = (unsigned short*)(ws + off_left16f);

        hipMemsetAsync(ws, 0, 64, stream);  // total

        int n2 = n_left * EMB / 2;
        convert_left_kernel<<<(n2 + 255) / 256, 256, 0, stream>>>(
            left, (unsigned*)left16, n2);
        init_bcur_kernel<<<1, 256, 0, stream>>>(bcur, nb, slot);
        {
            int nchunks = (n_edges + CHUNK - 1) / CHUNK;
            partition_kernel<<<nchunks, 256, 0, stream>>>(
                (const int2*)eidx, ew, n_edges, bcur, bsorted, total);
        }
        count_scan_kernel<<<1, 256, 0, stream>>>(bcur, sbase, nb, slot);
        local_rowsort_kernel<<<nb, 1024, 0, stream>>>(bsorted, bcur, sbase, offs,
                                                      sorted2, n_right, slot);
        {
            long long n_threads = (long long)n_right * EMB;
            int blocks = (int)((n_threads + 255) / 256);
            seg_gather_bf16_kernel<<<blocks, 256, 0, stream>>>(
                sorted2, offs, (const uint4*)left16, right, c, temp, total,
                out, n_right, n_edges, 0);
        }
        mlp_kernel<<<(n_right + MROWS - 1) / MROWS, 256, 0, stream>>>(
            W1, b1, W2, b2, out, n_right);
    } else if (common_ok && ws_size >= req_mid) {
        // ---------- mid path ----------
        char* ws = (char*)d_ws;
        float* total = (float*)ws;
        int* offs = (int*)(ws + m_off_offs);
        int* incl = (int*)(ws + m_off_incl);
        int* bsum = (int*)(ws + m_off_bsum);
        int2* sorted = (int2*)(ws + m_off_sorted);
        unsigned short* left16 = (unsigned short*)(ws + m_off_left16);

        hipMemsetAsync(ws, 0, m_off_offs + (size_t)n_right * 4, stream);

        int n2 = n_left * EMB / 2;
        convert_left_kernel<<<(n2 + 255) / 256, 256, 0, stream>>>(
            left, (unsigned*)left16, n2);
        hist_total_kernel<<<2048, 256, 0, stream>>>((const int2*)eidx, ew,
                                                    n_edges, offs, total);
        scan1_kernel<<<nblocks_scan, 1024, 0, stream>>>(offs, incl, bsum, n_right);
        scan2_kernel<<<1, 256, 0, stream>>>(bsum, nblocks_scan);
        scan3_kernel<<<(n_right + 255) / 256, 256, 0, stream>>>(incl, bsum, offs,
                                                                n_right);
        scatter_kernel<<<2048, 256, 0, stream>>>((const int2*)eidx, ew, n_edges,
                                                 offs, sorted);
        {
            long long n_threads = (long long)n_right * EMB;
            int blocks = (int)((n_threads + 255) / 256);
            seg_gather_bf16_kernel<<<blocks, 256, 0, stream>>>(
                sorted, offs, (const uint4*)left16, right, c, temp, total,
                out, n_right, n_edges, 1);
        }
        mlp_kernel<<<(n_right + MROWS - 1) / MROWS, 256, 0, stream>>>(
            W1, b1, W2, b2, out, n_right);
    } else {
        // ---------- fallback: atomic path ----------
        float* total = (float*)d_ws;
        hipMemsetAsync(d_out, 0, (size_t)out_size * sizeof(float), stream);
        hipMemsetAsync(d_ws, 0, sizeof(float), stream);
        sum_weights_kernel<<<2048, 256, 0, stream>>>(ew, n_edges, total);
        long long n_threads = (long long)n_edges * EMB;
        long long blocks = (n_threads + 255) / 256;
        edge_scatter_kernel<<<(int)blocks, 256, 0, stream>>>(
            eidx, ew, left, total, out, n_threads);
        int mblocks = (n_right + 255) / 256;
        fused_mlp_kernel<<<mblocks, 256, 0, stream>>>(right, c, temp, W1, b1, W2,
                                                      b2, out, n_right);
    }
}